// Round 2
// baseline (11032.437 us; speedup 1.0000x reference)
//
#include <hip/hip_runtime.h>
#include <hip/hip_bf16.h>
#include <math.h>

typedef long long i64;
typedef __hip_bfloat16 bf16;

#define NATOMS 60000
#define NEDGES 120000
#define NB     1024
#define DINF   88
#define DEF    32
#define EMB    256
#define NL     4
#define HIDF   512
#define NH     8
#define HD     64

__device__ __forceinline__ float toF(float v) { return v; }
__device__ __forceinline__ float toF(bf16 v) { return __bfloat162float(v); }
__device__ __forceinline__ void storeT(float* p, float v) { *p = v; }
__device__ __forceinline__ void storeT(bf16* p, float v) { *p = __float2bfloat16(v); }

// ---------------- GEMM: C = A @ W + bias (optional gather-A, resid, relu) -------------
// MODE 0: A is MxK row-major (type TA).
// MODE 1: row r = concat(h[dst[r]](256), h[src[r]](256), edge_attr[r](32)), K=544, A=h f32, A2=edge_attr.
// MODE 2: row r = concat(h[r](256), aggr[r](256)), K=512, A=h f32, A2=aggr f32.
template<int MODE, typename TA>
__device__ __forceinline__ float loadA(const TA* __restrict__ A, const float* __restrict__ A2,
                                       const int* __restrict__ gdst, const int* __restrict__ gsrc,
                                       int row, int k, int K) {
  if constexpr (MODE == 0) {
    return toF(A[(i64)row * K + k]);
  } else if constexpr (MODE == 1) {
    if (k < EMB)        return ((const float*)A)[(i64)gdst[row] * EMB + k];
    else if (k < 2*EMB) return ((const float*)A)[(i64)gsrc[row] * EMB + (k - EMB)];
    else                return A2[(i64)row * DEF + (k - 2*EMB)];
  } else {
    if (k < EMB) return ((const float*)A)[(i64)row * EMB + k];
    else         return A2[(i64)row * EMB + (k - EMB)];
  }
}

template<int MODE, typename TA, typename TO>
__global__ __launch_bounds__(256) void gemm_k(
    const TA* __restrict__ A, const float* __restrict__ A2,
    const int* __restrict__ gdst, const int* __restrict__ gsrc,
    const float* __restrict__ W, const float* __restrict__ bias,
    const float* __restrict__ resid,
    TO* __restrict__ C, int M, int K, int N, int doRelu)
{
  const int row0 = blockIdx.y * 64, col0 = blockIdx.x * 64;
  const int tid = threadIdx.x;
  const int ty = tid >> 4, tx = tid & 15;

  __shared__ float As[16][68];   // padded rows, conflict-free float4 reads
  __shared__ float Bs[16][64];

  float acc[4][4] = {};

  for (int k0 = 0; k0 < K; k0 += 16) {
    #pragma unroll
    for (int i = 0; i < 4; ++i) {
      int lin = tid + i * 256;
      int m = lin >> 4, kk = lin & 15;
      int row = row0 + m, k = k0 + kk;
      float v = 0.f;
      if (row < M && k < K) v = loadA<MODE, TA>(A, A2, gdst, gsrc, row, k, K);
      As[kk][m] = v;
    }
    #pragma unroll
    for (int i = 0; i < 4; ++i) {
      int lin = tid + i * 256;
      int kk = lin >> 6, n = lin & 63;
      int k = k0 + kk;
      Bs[kk][n] = (k < K) ? W[(i64)k * N + col0 + n] : 0.f;
    }
    __syncthreads();
    #pragma unroll
    for (int kk = 0; kk < 16; ++kk) {
      const float4 av = *(const float4*)&As[kk][ty * 4];
      const float4 bv = *(const float4*)&Bs[kk][tx * 4];
      const float a[4] = {av.x, av.y, av.z, av.w};
      const float b[4] = {bv.x, bv.y, bv.z, bv.w};
      #pragma unroll
      for (int i = 0; i < 4; ++i)
        #pragma unroll
        for (int j = 0; j < 4; ++j)
          acc[i][j] += a[i] * b[j];
    }
    __syncthreads();
  }

  #pragma unroll
  for (int i = 0; i < 4; ++i) {
    int row = row0 + ty * 4 + i;
    if (row < M) {
      #pragma unroll
      for (int j = 0; j < 4; ++j) {
        int col = col0 + tx * 4 + j;
        float v = acc[i][j];
        if (bias)  v += bias[col];
        if (resid) v += resid[(i64)row * N + col];
        if (doRelu) v = fmaxf(v, 0.f);
        storeT(&C[(i64)row * N + col], v);
      }
    }
  }
}

// ---------------- BatchNorm (training-mode batch stats) -------------------------------
template<typename T>
__global__ void bn_stats_k(const T* __restrict__ X, int M, float* __restrict__ st) {
  int c = threadIdx.x;  // EMB threads, one column each
  float s = 0.f, q = 0.f;
  for (int r = blockIdx.x; r < M; r += gridDim.x) {
    float v = toF(X[(i64)r * EMB + c]);
    s += v; q += v * v;
  }
  atomicAdd(&st[c], s);
  atomicAdd(&st[EMB + c], q);
}

// Y = (addIn? addIn : 0) + relu(gam*(X-mean)*rstd + bet)     (X,Y type T; addIn f32)
template<typename T>
__global__ __launch_bounds__(256) void bn_apply_k(
    const T* __restrict__ X, const float* __restrict__ addIn, T* __restrict__ Y,
    const float* __restrict__ st, const float* __restrict__ gam, const float* __restrict__ bet,
    i64 total, float invM)
{
  i64 i0 = ((i64)blockIdx.x * blockDim.x + threadIdx.x) * 4;
  i64 stride = (i64)gridDim.x * blockDim.x * 4;
  for (i64 i = i0; i < total; i += stride) {
    int c = (int)(i & (EMB - 1));
    float xv[4];
    if constexpr (sizeof(T) == 2) {
      ushort4 u = *(const ushort4*)((const unsigned short*)X + i);
      unsigned short us[4] = {u.x, u.y, u.z, u.w};
      #pragma unroll
      for (int j = 0; j < 4; ++j) xv[j] = __bfloat162float(*reinterpret_cast<const bf16*>(&us[j]));
    } else {
      float4 v = *(const float4*)((const float*)X + i);
      xv[0] = v.x; xv[1] = v.y; xv[2] = v.z; xv[3] = v.w;
    }
    float r[4];
    #pragma unroll
    for (int j = 0; j < 4; ++j) {
      int cc = c + j;
      float mean = st[cc] * invM;
      float var  = st[EMB + cc] * invM - mean * mean;
      float rs   = rsqrtf(var + 1e-5f);
      float t    = gam[cc] * (xv[j] - mean) * rs + bet[cc];
      t = fmaxf(t, 0.f);
      r[j] = addIn ? addIn[i + j] + t : t;
    }
    if constexpr (sizeof(T) == 2) {
      ushort4 o;
      bf16 b0 = __float2bfloat16(r[0]), b1 = __float2bfloat16(r[1]);
      bf16 b2 = __float2bfloat16(r[2]), b3 = __float2bfloat16(r[3]);
      o.x = *reinterpret_cast<unsigned short*>(&b0);
      o.y = *reinterpret_cast<unsigned short*>(&b1);
      o.z = *reinterpret_cast<unsigned short*>(&b2);
      o.w = *reinterpret_cast<unsigned short*>(&b3);
      *(ushort4*)((unsigned short*)Y + i) = o;
    } else {
      float4 o = {r[0], r[1], r[2], r[3]};
      *(float4*)((float*)Y + i) = o;
    }
  }
}

// ---------------- scatter-add aggregation (bf16 msgs -> f32 aggr) ---------------------
__global__ void scatter_k(const bf16* __restrict__ m, const int* __restrict__ dst,
                          float* __restrict__ aggr, i64 total) {
  i64 i0 = (i64)blockIdx.x * blockDim.x + threadIdx.x;
  i64 stride = (i64)gridDim.x * blockDim.x;
  for (i64 i = i0; i < total; i += stride) {
    int e = (int)(i >> 8);
    int c = (int)(i & 255);
    atomicAdd(&aggr[(i64)dst[e] * EMB + c], __bfloat162float(m[i]));
  }
}

// ---------------- global mean pool ----------------------------------------------------
__global__ void pool_sum_k(const float* __restrict__ h, const int* __restrict__ batch,
                           float* __restrict__ psum, float* __restrict__ pcnt) {
  i64 total = (i64)NATOMS * EMB;
  i64 i0 = (i64)blockIdx.x * blockDim.x + threadIdx.x;
  i64 stride = (i64)gridDim.x * blockDim.x;
  for (i64 i = i0; i < total; i += stride) {
    int a = (int)(i >> 8);
    int c = (int)(i & 255);
    int b = batch[a];
    atomicAdd(&psum[(i64)b * EMB + c], h[i]);
    if (c == 0) atomicAdd(&pcnt[b], 1.f);
  }
}

__global__ void pool_div_k(const float* __restrict__ psum, const float* __restrict__ pcnt,
                           float* __restrict__ g) {
  int i = blockIdx.x * blockDim.x + threadIdx.x;  // NB*EMB threads
  int b = i >> 8;
  g[i] = psum[i] / fmaxf(pcnt[b], 1.f);
}

// ---------------- attention core: per (b,head) outer-product softmax ------------------
__global__ __launch_bounds__(64) void attn_k(const float* __restrict__ Q, const float* __restrict__ K,
                                             const float* __restrict__ V, float* __restrict__ O) {
  int b = blockIdx.x >> 3, hh = blockIdx.x & 7;
  int d = threadIdx.x;
  __shared__ float Ks[HD], Vs[HD];
  Ks[d] = K[(i64)b * HIDF + hh * HD + d];
  Vs[d] = V[(i64)b * HIDF + hh * HD + d];
  __syncthreads();
  float q = Q[(i64)b * HIDF + hh * HD + d] * 0.125f;  // 1/sqrt(64)
  float mx = -1e30f;
  #pragma unroll
  for (int e = 0; e < HD; ++e) mx = fmaxf(mx, q * Ks[e]);
  float s = 0.f, o = 0.f;
  #pragma unroll
  for (int e = 0; e < HD; ++e) {
    float p = expf(q * Ks[e] - mx);
    s += p; o += p * Vs[e];
  }
  // torch permute(0,2,1,3).view: out feature = d*H + h
  O[(i64)b * HIDF + d * NH + hh] = o / s;
}

// ---------------- bind head + BCE loss + sigmoid --------------------------------------
__global__ __launch_bounds__(256) void bind_loss_k(const float* __restrict__ g, const float* __restrict__ W,
                                                   const float* __restrict__ bb, const float* __restrict__ tgt,
                                                   float* __restrict__ out) {
  int tid = threadIdx.x;
  float lsum = 0.f;
  for (int r = tid; r < NB; r += 256) {
    float a0 = bb[0], a1 = bb[1], a2 = bb[2];
    const float* gr = g + (i64)r * HIDF;
    for (int k = 0; k < HIDF; ++k) {
      float gv = gr[k];
      a0 += gv * W[k * 3 + 0];
      a1 += gv * W[k * 3 + 1];
      a2 += gv * W[k * 3 + 2];
    }
    float bv[3] = {a0, a1, a2};
    #pragma unroll
    for (int j = 0; j < 3; ++j) {
      float xv = bv[j], t = tgt[r * 3 + j];
      lsum += fmaxf(xv, 0.f) - xv * t + log1pf(expf(-fabsf(xv)));
      out[1 + r * 3 + j] = 1.f / (1.f + expf(-xv));
    }
  }
  __shared__ float red[256];
  red[tid] = lsum;
  __syncthreads();
  for (int s = 128; s > 0; s >>= 1) {
    if (tid < s) red[tid] += red[tid + s];
    __syncthreads();
  }
  if (tid == 0) out[0] = red[0] / (float)(NB * 3);
}

// ======================================================================================
template<typename TA, typename TO>
static inline void gemm0(const TA* A, const float* W, const float* b, const float* resid,
                         TO* C, int M, int K, int N, int relu, hipStream_t s) {
  dim3 grid(N / 64, (M + 63) / 64);
  gemm_k<0, TA, TO><<<grid, 256, 0, s>>>(A, nullptr, nullptr, nullptr, W, b, resid, C, M, K, N, relu);
}

extern "C" void kernel_launch(void* const* d_in, const int* in_sizes, int n_in,
                              void* d_out, int out_size, void* d_ws, size_t ws_size,
                              hipStream_t stream) {
  const float* x         = (const float*)d_in[0];
  const int*   ei        = (const int*)  d_in[1];
  const float* edge_attr = (const float*)d_in[2];
  const int*   batch     = (const int*)  d_in[3];
  const float* fp        = (const float*)d_in[4];
  const float* target    = (const float*)d_in[5];
  const float* lin_w     = (const float*)d_in[6];
  const float* lin_b     = (const float*)d_in[7];
  const float* msg_w1    = (const float*)d_in[8];
  const float* msg_b1    = (const float*)d_in[9];
  const float* msg_g1    = (const float*)d_in[10];
  const float* msg_be1   = (const float*)d_in[11];
  const float* msg_w2    = (const float*)d_in[12];
  const float* msg_b2    = (const float*)d_in[13];
  const float* msg_g2    = (const float*)d_in[14];
  const float* msg_be2   = (const float*)d_in[15];
  const float* upd_w1    = (const float*)d_in[16];
  const float* upd_b1    = (const float*)d_in[17];
  const float* upd_g1    = (const float*)d_in[18];
  const float* upd_be1   = (const float*)d_in[19];
  const float* upd_w2    = (const float*)d_in[20];
  const float* upd_b2    = (const float*)d_in[21];
  const float* upd_g2    = (const float*)d_in[22];
  const float* upd_be2   = (const float*)d_in[23];
  const float* gl_w1     = (const float*)d_in[24];
  const float* gl_b1     = (const float*)d_in[25];
  const float* gl_w2     = (const float*)d_in[26];
  const float* gl_b2     = (const float*)d_in[27];
  const float* gl_w3     = (const float*)d_in[28];
  const float* gl_b3     = (const float*)d_in[29];
  const float* fp_w      = (const float*)d_in[30];
  const float* fp_b      = (const float*)d_in[31];
  const float* att_w     = (const float*)d_in[32];
  const float* att_b     = (const float*)d_in[33];
  const float* bind_w    = (const float*)d_in[34];
  const float* bind_b    = (const float*)d_in[35];

  const int* src = ei;            // edge_index row 0 = source j
  const int* dst = ei + NEDGES;   // edge_index row 1 = target i

  // ---- workspace layout: 8192 + 3*15,360,000 floats = 184.4 MB ----
  float* wsf  = (float*)d_ws;
  float* stats = wsf;                                  // 16 slots x [sum(256), sumsq(256)]
  float* h     = wsf + 8192;                           // NATOMS*256 f32
  float* R2f   = h + (i64)NATOMS * EMB;                // region 2 (61.44 MB)
  float* R3f   = R2f + (i64)NATOMS * EMB;              // region 3 (61.44 MB)
  bf16*  R2b   = (bf16*)R2f;                           // as E*256 bf16
  bf16*  R3b   = (bf16*)R3f;

  // head scratch overlays R2 (dead after MPNN)
  float* psum = R2f;                        // NB*EMB
  float* pcnt = psum + (i64)NB * EMB;       // NB
  float* g0   = pcnt + NB;                  // NB*EMB
  float* gh1  = g0 + (i64)NB * EMB;         // NB*1024
  float* gh2  = gh1 + (i64)NB * 1024;       // NB*1024
  float* g3   = gh2 + (i64)NB * 1024;       // NB*512
  float* fpf  = g3 + (i64)NB * HIDF;
  float* Qb   = fpf + (i64)NB * HIDF;
  float* Kb   = Qb + (i64)NB * HIDF;
  float* Vb   = Kb + (i64)NB * HIDF;
  float* Ob   = Vb + (i64)NB * HIDF;
  float* gc1  = Ob + (i64)NB * HIDF;
  float* gc2  = gc1 + (i64)NB * HIDF;

  // zero BN stat accumulators
  hipMemsetAsync(stats, 0, 8192 * sizeof(float), stream);

  // h = x @ lin_w + lin_b
  gemm0(x, lin_w, lin_b, (const float*)nullptr, h, NATOMS, DINF, EMB, 0, stream);

  dim3 gridE(EMB / 64, (NEDGES + 63) / 64);
  dim3 gridN(EMB / 64, (NATOMS + 63) / 64);

  for (int l = 0; l < NL; ++l) {
    const float* w1  = msg_w1 + (i64)l * (2 * EMB + DEF) * EMB;
    const float* b1  = msg_b1 + l * EMB;
    const float* w2  = msg_w2 + (i64)l * EMB * EMB;
    const float* b2  = msg_b2 + l * EMB;
    const float* uw1 = upd_w1 + (i64)l * 2 * EMB * EMB;
    const float* ub1 = upd_b1 + l * EMB;
    const float* uw2 = upd_w2 + (i64)l * EMB * EMB;
    const float* ub2 = upd_b2 + l * EMB;
    float* st;

    // m1 = concat(h[dst], h[src], edge_attr) @ w1 + b1  -> R2 (bf16)
    gemm_k<1, float, bf16><<<gridE, 256, 0, stream>>>(h, edge_attr, dst, src, w1, b1, nullptr,
                                                      R2b, NEDGES, 2 * EMB + DEF, EMB, 0);
    st = stats + (l * 4 + 0) * 2 * EMB;
    bn_stats_k<bf16><<<768, EMB, 0, stream>>>(R2b, NEDGES, st);
    bn_apply_k<bf16><<<2048, 256, 0, stream>>>(R2b, nullptr, R2b, st, msg_g1 + l * EMB, msg_be1 + l * EMB,
                                               (i64)NEDGES * EMB, 1.f / NEDGES);
    // m2 = m1r @ w2 + b2  -> R3 (bf16)
    gemm_k<0, bf16, bf16><<<gridE, 256, 0, stream>>>(R2b, nullptr, nullptr, nullptr, w2, b2, nullptr,
                                                     R3b, NEDGES, EMB, EMB, 0);
    st = stats + (l * 4 + 1) * 2 * EMB;
    bn_stats_k<bf16><<<768, EMB, 0, stream>>>(R3b, NEDGES, st);
    bn_apply_k<bf16><<<2048, 256, 0, stream>>>(R3b, nullptr, R3b, st, msg_g2 + l * EMB, msg_be2 + l * EMB,
                                               (i64)NEDGES * EMB, 1.f / NEDGES);
    // aggr = segment_sum(m2, dst)  -> R2 (f32)
    hipMemsetAsync(R2f, 0, (size_t)NATOMS * EMB * sizeof(float), stream);
    scatter_k<<<4096, 256, 0, stream>>>(R3b, dst, R2f, (i64)NEDGES * EMB);
    // u1 = concat(h, aggr) @ uw1 + ub1  -> R3 (f32)
    gemm_k<2, float, float><<<gridN, 256, 0, stream>>>(h, R2f, nullptr, nullptr, uw1, ub1, nullptr,
                                                       R3f, NATOMS, 2 * EMB, EMB, 0);
    st = stats + (l * 4 + 2) * 2 * EMB;
    bn_stats_k<float><<<768, EMB, 0, stream>>>(R3f, NATOMS, st);
    bn_apply_k<float><<<2048, 256, 0, stream>>>(R3f, nullptr, R3f, st, upd_g1 + l * EMB, upd_be1 + l * EMB,
                                                (i64)NATOMS * EMB, 1.f / NATOMS);
    // u2 = u1r @ uw2 + ub2  -> R2 (f32)
    gemm_k<0, float, float><<<gridN, 256, 0, stream>>>(R3f, nullptr, nullptr, nullptr, uw2, ub2, nullptr,
                                                       R2f, NATOMS, EMB, EMB, 0);
    st = stats + (l * 4 + 3) * 2 * EMB;
    bn_stats_k<float><<<768, EMB, 0, stream>>>(R2f, NATOMS, st);
    // h = h + relu(bn(u2))
    bn_apply_k<float><<<2048, 256, 0, stream>>>(R2f, h, h, st, upd_g2 + l * EMB, upd_be2 + l * EMB,
                                                (i64)NATOMS * EMB, 1.f / NATOMS);
  }

  // global mean pool (psum/pcnt overlay R2; zero them first)
  hipMemsetAsync(psum, 0, (size_t)(NB * EMB + NB) * sizeof(float), stream);
  pool_sum_k<<<2048, 256, 0, stream>>>(h, batch, psum, pcnt);
  pool_div_k<<<(NB * EMB) / 256, 256, 0, stream>>>(psum, pcnt, g0);

  // graph MLP
  gemm0(g0, gl_w1, gl_b1, (const float*)nullptr, gh1, NB, EMB, 1024, 1, stream);
  gemm0(gh1, gl_w2, gl_b2, (const float*)nullptr, gh2, NB, 1024, 1024, 1, stream);
  gemm0(gh2, gl_w3, gl_b3, (const float*)nullptr, g3, NB, 1024, HIDF, 0, stream);
  // fingerprint branch
  gemm0(fp, fp_w, fp_b, (const float*)nullptr, fpf, NB, 2048, HIDF, 1, stream);

  // attention 0: Q from fpf, K/V from g3; residual g3
  {
    const float* aw = att_w;                 // (2,4,512,512)
    const float* ab = att_b;                 // (2,4,512)
    gemm0(fpf, aw + (i64)0 * HIDF * HIDF, ab + 0 * HIDF, (const float*)nullptr, Qb, NB, HIDF, HIDF, 0, stream);
    gemm0(g3,  aw + (i64)1 * HIDF * HIDF, ab + 1 * HIDF, (const float*)nullptr, Kb, NB, HIDF, HIDF, 0, stream);
    gemm0(g3,  aw + (i64)2 * HIDF * HIDF, ab + 2 * HIDF, (const float*)nullptr, Vb, NB, HIDF, HIDF, 0, stream);
    attn_k<<<NB * NH, 64, 0, stream>>>(Qb, Kb, Vb, Ob);
    gemm0(Ob,  aw + (i64)3 * HIDF * HIDF, ab + 3 * HIDF, g3, gc1, NB, HIDF, HIDF, 0, stream);
  }
  // attention 1: self-attention on gc1, no residual
  {
    const float* aw = att_w + (i64)4 * HIDF * HIDF;
    const float* ab = att_b + 4 * HIDF;
    gemm0(gc1, aw + (i64)0 * HIDF * HIDF, ab + 0 * HIDF, (const float*)nullptr, Qb, NB, HIDF, HIDF, 0, stream);
    gemm0(gc1, aw + (i64)1 * HIDF * HIDF, ab + 1 * HIDF, (const float*)nullptr, Kb, NB, HIDF, HIDF, 0, stream);
    gemm0(gc1, aw + (i64)2 * HIDF * HIDF, ab + 2 * HIDF, (const float*)nullptr, Vb, NB, HIDF, HIDF, 0, stream);
    attn_k<<<NB * NH, 64, 0, stream>>>(Qb, Kb, Vb, Ob);
    gemm0(Ob,  aw + (i64)3 * HIDF * HIDF, ab + 3 * HIDF, (const float*)nullptr, gc2, NB, HIDF, HIDF, 0, stream);
  }

  // bind + loss + sigmoid
  bind_loss_k<<<1, 256, 0, stream>>>(gc2, bind_w, bind_b, target, (float*)d_out);
}

// Round 4
// 2181.720 us; speedup vs baseline: 5.0568x; 5.0568x over previous
//
#include <hip/hip_runtime.h>
#include <hip/hip_bf16.h>
#include <math.h>

typedef long long i64;
typedef __hip_bfloat16 bf16;
typedef __attribute__((ext_vector_type(8))) short bfx8;
typedef __attribute__((ext_vector_type(4))) float f32x4;

#define NATOMS 60000
#define NEDGES 120000
#define NB     1024
#define EMB    256
#define NL     4
#define HIDF   512
#define NH     8
#define HD     64

__device__ __forceinline__ void storeT(float* p, float v) { *p = v; }
__device__ __forceinline__ void storeT(bf16* p, float v) { *p = __float2bfloat16(v); }

__device__ __forceinline__ void gl_lds16(const void* g, void* l) {
  __builtin_amdgcn_global_load_lds((const __attribute__((address_space(1))) void*)g,
                                   (__attribute__((address_space(3))) void*)l, 16, 0, 0);
}

// ================= MFMA GEMM: C = A @ Wt^T (+bias)(+resid)(relu?), fused BN stats =====
// A logical MxKp bf16 (Kp mult of 64, zero-padded); Wt is N x Kp bf16 (pre-transposed).
// MODE 0: A row-major MxKp.
// MODE 1: row r = concat(h[dst[r]](256), h[src[r]](256), ea_pad[r](64)), Kp=576.
// MODE 2: row r = concat(h[r](256), aggr[r](256)), Kp=512.
// Tile 128x128, BK=64, 4 waves (each 64x64 as 4x4 frags of 16x16x32).
// LDS layout: [r][64 bf16] with 16B-slot XOR swizzle (slot ^ (r&7)); staged via
// global_load_lds with inverse-swizzled global source (linear LDS dest).
template<int MODE, typename TO>
__global__ __launch_bounds__(256, 2) void mgemm_k(
    const bf16* __restrict__ A, const bf16* __restrict__ A2,
    const int* __restrict__ gdst, const int* __restrict__ gsrc,
    const bf16* __restrict__ Wt,
    const float* __restrict__ bias, const float* __restrict__ resid,
    TO* __restrict__ C, float* __restrict__ stats,
    int M, int Kp, int N, int doRelu)
{
  __shared__ short As[128 * 64];
  __shared__ short Bs[128 * 64];
  __shared__ float sSum[128], sSq[128];

  const int tid = threadIdx.x;
  const int w = tid >> 6, lane = tid & 63;
  const int wr = w >> 1, wc = w & 1;
  const int row0 = blockIdx.y * 128, col0 = blockIdx.x * 128;

  int rI[4], slotG[4], dIdx[4], sIdx[4], rClamp[4];
  #pragma unroll
  for (int i = 0; i < 4; ++i) {
    int lin = i * 256 + tid;
    int r = lin >> 3, sl = lin & 7;
    rI[i] = r;
    slotG[i] = sl ^ (r & 7);
    rClamp[i] = min(row0 + r, M - 1);
    if (MODE == 1) { dIdx[i] = gdst[rClamp[i]]; sIdx[i] = gsrc[rClamp[i]]; }
  }

  f32x4 acc[4][4];
  #pragma unroll
  for (int a = 0; a < 4; ++a)
    #pragma unroll
    for (int b = 0; b < 4; ++b)
      acc[a][b] = (f32x4){0.f, 0.f, 0.f, 0.f};

  const int KT = Kp >> 6;
  for (int kt = 0; kt < KT; ++kt) {
    const int k0 = kt << 6;
    // ---- stage A (4 x 16B per thread) ----
    #pragma unroll
    for (int i = 0; i < 4; ++i) {
      const bf16* g;
      int ko = slotG[i] * 8;
      if constexpr (MODE == 0) {
        g = A + (i64)rClamp[i] * Kp + k0 + ko;
      } else if constexpr (MODE == 1) {
        if (k0 < 256)      g = A  + (i64)dIdx[i] * EMB + k0 + ko;
        else if (k0 < 512) g = A  + (i64)sIdx[i] * EMB + (k0 - 256) + ko;
        else               g = A2 + (i64)rClamp[i] * 64 + (k0 - 512) + ko;
      } else {
        g = (k0 < 256) ? A  + (i64)rClamp[i] * EMB + k0 + ko
                       : A2 + (i64)rClamp[i] * EMB + (k0 - 256) + ko;
      }
      gl_lds16(g, (char*)&As[0] + i * 4096 + w * 1024);
    }
    // ---- stage B ----
    #pragma unroll
    for (int i = 0; i < 4; ++i) {
      const bf16* g = Wt + (i64)(col0 + rI[i]) * Kp + k0 + slotG[i] * 8;
      gl_lds16(g, (char*)&Bs[0] + i * 4096 + w * 1024);
    }
    __syncthreads();   // drains vmcnt before LDS use

    #pragma unroll
    for (int ks = 0; ks < 2; ++ks) {
      bfx8 af[4], bf_[4];
      #pragma unroll
      for (int mi = 0; mi < 4; ++mi) {
        int r = wr * 64 + mi * 16 + (lane & 15);
        int q = ks * 4 + (lane >> 4);
        int s = q ^ (r & 7);
        af[mi] = *(const bfx8*)&As[r * 64 + s * 8];
      }
      #pragma unroll
      for (int ni = 0; ni < 4; ++ni) {
        int n = wc * 64 + ni * 16 + (lane & 15);
        int q = ks * 4 + (lane >> 4);
        int s = q ^ (n & 7);
        bf_[ni] = *(const bfx8*)&Bs[n * 64 + s * 8];
      }
      #pragma unroll
      for (int mi = 0; mi < 4; ++mi)
        #pragma unroll
        for (int ni = 0; ni < 4; ++ni)
          acc[mi][ni] = __builtin_amdgcn_mfma_f32_16x16x32_bf16(af[mi], bf_[ni], acc[mi][ni], 0, 0, 0);
    }
    __syncthreads();
  }

  // ---- epilogue: C store (C/D layout: col = lane&15, row = (lane>>4)*4 + j) ----
  #pragma unroll
  for (int mi = 0; mi < 4; ++mi) {
    #pragma unroll
    for (int j = 0; j < 4; ++j) {
      int row = row0 + wr * 64 + mi * 16 + (lane >> 4) * 4 + j;
      if (row < M) {
        #pragma unroll
        for (int ni = 0; ni < 4; ++ni) {
          int col = col0 + wc * 64 + ni * 16 + (lane & 15);
          float v = acc[mi][ni][j];
          if (bias)  v += bias[col];
          if (resid) v += resid[(i64)row * N + col];
          if (doRelu) v = fmaxf(v, 0.f);
          storeT(&C[(i64)row * N + col], v);
        }
      }
    }
  }

  // ---- fused BN stats (sum, sumsq per column; N==256 layout [256 sum][256 sq]) ----
  if (stats) {
    if (tid < 128) { sSum[tid] = 0.f; sSq[tid] = 0.f; }
    __syncthreads();
    #pragma unroll
    for (int ni = 0; ni < 4; ++ni) {
      float ps = 0.f, pq = 0.f;
      #pragma unroll
      for (int mi = 0; mi < 4; ++mi)
        #pragma unroll
        for (int j = 0; j < 4; ++j) {
          int row = row0 + wr * 64 + mi * 16 + (lane >> 4) * 4 + j;
          if (row < M) { float v = acc[mi][ni][j]; ps += v; pq += v * v; }
        }
      ps += __shfl_xor(ps, 16); ps += __shfl_xor(ps, 32);
      pq += __shfl_xor(pq, 16); pq += __shfl_xor(pq, 32);
      if (lane < 16) {
        int c = wc * 64 + ni * 16 + lane;
        atomicAdd(&sSum[c], ps); atomicAdd(&sSq[c], pq);
      }
    }
    __syncthreads();
    if (tid < 128) {
      atomicAdd(&stats[col0 + tid], sSum[tid]);
      atomicAdd(&stats[256 + col0 + tid], sSq[tid]);
    }
  }
}

// ================= weight transpose+convert+pad: W f32 [K][N] -> Wt bf16 [N][Kp] ======
struct WDesc { const float* W; bf16* Wt; int K, N, Kp, bStart; };
struct WPack { WDesc d[29]; int cnt; };

__global__ __launch_bounds__(256) void wcvt_k(WPack p) {
  int bid = blockIdx.x;
  int di = 0;
  for (int i = 1; i < 29; ++i) if (i < p.cnt && bid >= p.d[i].bStart) di = i;
  WDesc wd = p.d[di];
  int t = bid - wd.bStart;
  int tilesN = wd.N >> 5;
  int tn = t % tilesN, tk = t / tilesN;
  __shared__ float tl[32][33];
  int tx = threadIdx.x & 31, ty = threadIdx.x >> 5;
  #pragma unroll
  for (int ii = 0; ii < 4; ++ii) {
    int k = tk * 32 + ty + ii * 8;
    int n = tn * 32 + tx;
    tl[ty + ii * 8][tx] = (k < wd.K) ? wd.W[(i64)k * wd.N + n] : 0.f;
  }
  __syncthreads();
  #pragma unroll
  for (int ii = 0; ii < 4; ++ii) {
    int n = tn * 32 + ty + ii * 8;
    int k = tk * 32 + tx;
    wd.Wt[(i64)n * wd.Kp + k] = __float2bfloat16(tl[tx][ty + ii * 8]);
  }
}

// ================= pad + convert f32 [rows][sc] -> bf16 [rows][dc], zero-pad ==========
__global__ void padcvt_k(const float* __restrict__ S, bf16* __restrict__ D,
                         int rows, int sc, int dc) {
  i64 total = (i64)rows * dc;
  for (i64 i = (i64)blockIdx.x * blockDim.x + threadIdx.x; i < total;
       i += (i64)gridDim.x * blockDim.x) {
    int r = (int)(i / dc), c = (int)(i % dc);
    D[i] = __float2bfloat16(c < sc ? S[(i64)r * sc + c] : 0.f);
  }
}

// ================= plain f32 -> bf16 convert ==========================================
__global__ void cvt_k(const float* __restrict__ S, bf16* __restrict__ D, i64 total) {
  i64 i0 = ((i64)blockIdx.x * blockDim.x + threadIdx.x) * 4;
  i64 stride = (i64)gridDim.x * blockDim.x * 4;
  for (i64 i = i0; i < total; i += stride) {
    float4 v = *(const float4*)(S + i);
    D[i + 0] = __float2bfloat16(v.x);
    D[i + 1] = __float2bfloat16(v.y);
    D[i + 2] = __float2bfloat16(v.z);
    D[i + 3] = __float2bfloat16(v.w);
  }
}

// ================= BN apply: Y = (add?h:0) + relu(gam*(X-mean)*rstd + bet), bf16 ======
template<int HASADD>
__global__ __launch_bounds__(256) void bnap_k(
    const bf16* __restrict__ X, const bf16* __restrict__ addIn, bf16* __restrict__ Y,
    const float* __restrict__ st, const float* __restrict__ gam, const float* __restrict__ bet,
    i64 total, float invM)
{
  __shared__ float sc[256], sh[256];
  {
    int c = threadIdx.x;
    float mean = st[c] * invM;
    float var  = st[256 + c] * invM - mean * mean;
    float rs   = rsqrtf(var + 1e-5f);
    float s    = gam[c] * rs;
    sc[c] = s; sh[c] = bet[c] - mean * s;
  }
  __syncthreads();
  i64 i0 = ((i64)blockIdx.x * blockDim.x + threadIdx.x) * 8;
  i64 stride = (i64)gridDim.x * blockDim.x * 8;
  for (i64 i = i0; i < total; i += stride) {
    bfx8 xv = *(const bfx8*)((const short*)X + i);
    bfx8 av;
    if (HASADD) av = *(const bfx8*)((const short*)addIn + i);
    int c0 = (int)(i & 255);
    bfx8 o;
    #pragma unroll
    for (int j = 0; j < 8; ++j) {
      unsigned short u = (unsigned short)xv[j];
      float x = __bfloat162float(*reinterpret_cast<const bf16*>(&u));
      int c = c0 + j;
      float t = fmaxf(x * sc[c] + sh[c], 0.f);
      if (HASADD) {
        unsigned short ua = (unsigned short)av[j];
        t += __bfloat162float(*reinterpret_cast<const bf16*>(&ua));
      }
      bf16 b = __float2bfloat16(t);
      o[j] = (short)*reinterpret_cast<unsigned short*>(&b);
    }
    *(bfx8*)((short*)Y + i) = o;
  }
}

// ================= scatter-add aggregation (bf16 msgs -> f32 aggr) ====================
__global__ void scatter_k(const bf16* __restrict__ m, const int* __restrict__ dst,
                          float* __restrict__ aggr, i64 total) {
  i64 i0 = (i64)blockIdx.x * blockDim.x + threadIdx.x;
  i64 stride = (i64)gridDim.x * blockDim.x;
  for (i64 i = i0; i < total; i += stride) {
    int e = (int)(i >> 8);
    int c = (int)(i & 255);
    atomicAdd(&aggr[(i64)dst[e] * EMB + c], __bfloat162float(m[i]));
  }
}

// ================= per-graph mean pool (batch sorted; binary-search segment) ==========
__global__ __launch_bounds__(256) void pool_seg_k(const bf16* __restrict__ h,
                                                  const int* __restrict__ batch,
                                                  bf16* __restrict__ g0b) {
  int b = blockIdx.x, c = threadIdx.x;
  int lo = 0, hi = NATOMS;
  while (lo < hi) { int mid = (lo + hi) >> 1; if (batch[mid] < b) lo = mid + 1; else hi = mid; }
  int s = lo;
  hi = NATOMS;
  while (lo < hi) { int mid = (lo + hi) >> 1; if (batch[mid] < b + 1) lo = mid + 1; else hi = mid; }
  int e = lo;
  float acc = 0.f;
  for (int r = s; r < e; ++r) acc += __bfloat162float(h[(i64)r * EMB + c]);
  g0b[b * EMB + c] = __float2bfloat16(acc / (float)max(e - s, 1));
}

// ================= attention core: per (b,head) outer-product softmax =================
__global__ __launch_bounds__(64) void attn_k(const float* __restrict__ Q, const float* __restrict__ K,
                                             const float* __restrict__ V, bf16* __restrict__ O) {
  int b = blockIdx.x >> 3, hh = blockIdx.x & 7;
  int d = threadIdx.x;
  __shared__ float Ks[HD], Vs[HD];
  Ks[d] = K[(i64)b * HIDF + hh * HD + d];
  Vs[d] = V[(i64)b * HIDF + hh * HD + d];
  __syncthreads();
  float q = Q[(i64)b * HIDF + hh * HD + d] * 0.125f;
  float mx = -1e30f;
  #pragma unroll
  for (int e = 0; e < HD; ++e) mx = fmaxf(mx, q * Ks[e]);
  float s = 0.f, o = 0.f;
  #pragma unroll
  for (int e = 0; e < HD; ++e) {
    float p = expf(q * Ks[e] - mx);
    s += p; o += p * Vs[e];
  }
  O[(i64)b * HIDF + d * NH + hh] = __float2bfloat16(o / s);  // (head_dim, head) flatten
}

// ================= bind head + BCE loss + sigmoid =====================================
__global__ __launch_bounds__(256) void bind_loss_k(const float* __restrict__ g, const float* __restrict__ W,
                                                   const float* __restrict__ bb, const float* __restrict__ tgt,
                                                   float* __restrict__ out) {
  int tid = threadIdx.x;
  float lsum = 0.f;
  for (int r = tid; r < NB; r += 256) {
    float a0 = bb[0], a1 = bb[1], a2 = bb[2];
    const float* gr = g + (i64)r * HIDF;
    for (int k = 0; k < HIDF; ++k) {
      float gv = gr[k];
      a0 += gv * W[k * 3 + 0];
      a1 += gv * W[k * 3 + 1];
      a2 += gv * W[k * 3 + 2];
    }
    float bv[3] = {a0, a1, a2};
    #pragma unroll
    for (int j = 0; j < 3; ++j) {
      float xv = bv[j], t = tgt[r * 3 + j];
      lsum += fmaxf(xv, 0.f) - xv * t + log1pf(expf(-fabsf(xv)));
      out[1 + r * 3 + j] = 1.f / (1.f + expf(-xv));
    }
  }
  __shared__ float red[256];
  red[tid] = lsum;
  __syncthreads();
  for (int s = 128; s > 0; s >>= 1) {
    if (tid < s) red[tid] += red[tid + s];
    __syncthreads();
  }
  if (tid == 0) out[0] = red[0] / (float)(NB * 3);
}

// ======================================================================================
extern "C" void kernel_launch(void* const* d_in, const int* in_sizes, int n_in,
                              void* d_out, int out_size, void* d_ws, size_t ws_size,
                              hipStream_t stream) {
  const float* x         = (const float*)d_in[0];
  const int*   ei        = (const int*)  d_in[1];
  const float* edge_attr = (const float*)d_in[2];
  const int*   batch     = (const int*)  d_in[3];
  const float* fp        = (const float*)d_in[4];
  const float* target    = (const float*)d_in[5];
  const float* lin_w     = (const float*)d_in[6];
  const float* lin_b     = (const float*)d_in[7];
  const float* msg_w1    = (const float*)d_in[8];
  const float* msg_g1    = (const float*)d_in[10];
  const float* msg_be1   = (const float*)d_in[11];
  const float* msg_w2    = (const float*)d_in[12];
  const float* msg_g2    = (const float*)d_in[14];
  const float* msg_be2   = (const float*)d_in[15];
  const float* upd_w1    = (const float*)d_in[16];
  const float* upd_g1    = (const float*)d_in[18];
  const float* upd_be1   = (const float*)d_in[19];
  const float* upd_w2    = (const float*)d_in[20];
  const float* upd_g2    = (const float*)d_in[22];
  const float* upd_be2   = (const float*)d_in[23];
  const float* gl_w1     = (const float*)d_in[24];
  const float* gl_b1     = (const float*)d_in[25];
  const float* gl_w2     = (const float*)d_in[26];
  const float* gl_b2     = (const float*)d_in[27];
  const float* gl_w3     = (const float*)d_in[28];
  const float* gl_b3     = (const float*)d_in[29];
  const float* fp_w      = (const float*)d_in[30];
  const float* fp_b      = (const float*)d_in[31];
  const float* att_w     = (const float*)d_in[32];
  const float* att_b     = (const float*)d_in[33];
  const float* bind_w    = (const float*)d_in[34];
  const float* bind_b    = (const float*)d_in[35];

  const int* src = ei;            // row 0 = source j
  const int* dst = ei + NEDGES;   // row 1 = target i

  // ---- workspace layout (total ~174 MB, < proven-safe 184 MB) ----
  char* base = (char*)d_ws;
  float* stats = (float*)base;                                   // 8192 f32 (16 slots x 512)
  char* p = base + 8192 * 4;
  bf16* h_bf  = (bf16*)p; p += (i64)NATOMS * EMB * 2;            // 30.72 MB
  bf16* ea_bf = (bf16*)p; p += (i64)NEDGES * 64 * 2;             // 15.36 MB
  bf16* wt    = (bf16*)p; p += 6651904LL * 2;                    // 12.7 MB weight pool
  char* R1 = p; p += 61440000LL;                                 // 61.44 MB
  char* R2 = p;                                                  // 61.44 MB

  // weight pool carve
  bf16* Wt_lin = wt; wt += 256 * 128;
  bf16 *Wt_m1[NL], *Wt_m2[NL], *Wt_u1[NL], *Wt_u2[NL];
  for (int l = 0; l < NL; ++l) { Wt_m1[l] = wt; wt += 256 * 576; }
  for (int l = 0; l < NL; ++l) { Wt_m2[l] = wt; wt += 256 * 256; }
  for (int l = 0; l < NL; ++l) { Wt_u1[l] = wt; wt += 256 * 512; }
  for (int l = 0; l < NL; ++l) { Wt_u2[l] = wt; wt += 256 * 256; }
  bf16* Wt_gl1 = wt; wt += 1024 * 256;
  bf16* Wt_gl2 = wt; wt += 1024 * 1024;
  bf16* Wt_gl3 = wt; wt += 512 * 1024;
  bf16* Wt_fp  = wt; wt += 512 * 2048;
  bf16* Wt_att[8];
  for (int i = 0; i < 8; ++i) { Wt_att[i] = wt; wt += 512 * 512; }

  // region aliases
  bf16*  x_bf  = (bf16*)R2;         // 60000x128
  bf16*  m1b   = (bf16*)R1;         // E x 256
  bf16*  m2b   = (bf16*)R2;         // E x 256
  float* aggr  = (float*)R1;        // N x 256 f32
  bf16*  aggrb = (bf16*)R2;         // N x 256
  bf16*  u1b   = (bf16*)(R2 + (i64)NATOMS * EMB * 2);
  bf16*  u2b   = (bf16*)R1;

  // head scratch overlays R1 (MPNN edge buffers dead)
  bf16*  g0b  = (bf16*)R1;
  bf16*  gh1b = g0b + (i64)NB * EMB;
  bf16*  gh2b = gh1b + (i64)NB * 1024;
  float* g3   = (float*)(gh2b + (i64)NB * 1024);
  bf16*  g3b  = (bf16*)(g3 + (i64)NB * HIDF);
  bf16*  fpb  = g3b + (i64)NB * HIDF;
  bf16*  fpfb = fpb + (i64)NB * 2048;
  float* Qb   = (float*)(fpfb + (i64)NB * HIDF);
  float* Kb   = Qb + (i64)NB * HIDF;
  float* Vb   = Kb + (i64)NB * HIDF;
  bf16*  Obb  = (bf16*)(Vb + (i64)NB * HIDF);
  float* gc1  = (float*)(Obb + (i64)NB * HIDF);
  bf16*  gc1b = (bf16*)(gc1 + (i64)NB * HIDF);
  float* gc2  = (float*)(gc1b + (i64)NB * HIDF);

  hipMemsetAsync(stats, 0, 8192 * 4, stream);

  // ---- weight convert (one batched launch) ----
  WPack pk; int bs = 0, di = 0;
  auto addW = [&](const float* Wp, bf16* Wtp, int K, int N, int Kp) {
    pk.d[di].W = Wp; pk.d[di].Wt = Wtp; pk.d[di].K = K; pk.d[di].N = N;
    pk.d[di].Kp = Kp; pk.d[di].bStart = bs;
    bs += (Kp / 32) * (N / 32); ++di;
  };
  addW(lin_w, Wt_lin, 88, 256, 128);
  for (int l = 0; l < NL; ++l) addW(msg_w1 + (i64)l * 544 * 256, Wt_m1[l], 544, 256, 576);
  for (int l = 0; l < NL; ++l) addW(msg_w2 + (i64)l * 256 * 256, Wt_m2[l], 256, 256, 256);
  for (int l = 0; l < NL; ++l) addW(upd_w1 + (i64)l * 512 * 256, Wt_u1[l], 512, 256, 512);
  for (int l = 0; l < NL; ++l) addW(upd_w2 + (i64)l * 256 * 256, Wt_u2[l], 256, 256, 256);
  addW(gl_w1, Wt_gl1, 256, 1024, 256);
  addW(gl_w2, Wt_gl2, 1024, 1024, 1024);
  addW(gl_w3, Wt_gl3, 1024, 512, 1024);
  addW(fp_w, Wt_fp, 2048, 512, 2048);
  for (int i = 0; i < 8; ++i) addW(att_w + (i64)i * 512 * 512, Wt_att[i], 512, 512, 512);
  pk.cnt = di;
  wcvt_k<<<bs, 256, 0, stream>>>(pk);

  padcvt_k<<<2048, 256, 0, stream>>>(x, x_bf, NATOMS, 88, 128);
  padcvt_k<<<2048, 256, 0, stream>>>(edge_attr, ea_bf, NEDGES, 32, 64);

  dim3 gE(2, (NEDGES + 127) / 128), gN(2, (NATOMS + 127) / 128);

  // h = x @ lin_w + lin_b
  mgemm_k<0, bf16><<<gN, 256, 0, stream>>>(x_bf, nullptr, nullptr, nullptr, Wt_lin,
      lin_b, nullptr, h_bf, nullptr, NATOMS, 128, 256, 0);

  for (int l = 0; l < NL; ++l) {
    float* st0 = stats + (l * 4 + 0) * 512;
    float* st1 = stats + (l * 4 + 1) * 512;
    float* st2 = stats + (l * 4 + 2) * 512;
    float* st3 = stats + (l * 4 + 3) * 512;
    // m1 (bias skipped: cancels through BN)
    mgemm_k<1, bf16><<<gE, 256, 0, stream>>>(h_bf, ea_bf, dst, src, Wt_m1[l],
        nullptr, nullptr, m1b, st0, NEDGES, 576, 256, 0);
    bnap_k<0><<<2048, 256, 0, stream>>>(m1b, nullptr, m1b, st0,
        msg_g1 + l * EMB, msg_be1 + l * EMB, (i64)NEDGES * EMB, 1.f / NEDGES);
    // m2
    mgemm_k<0, bf16><<<gE, 256, 0, stream>>>(m1b, nullptr, nullptr, nullptr, Wt_m2[l],
        nullptr, nullptr, m2b, st1, NEDGES, 256, 256, 0);
    bnap_k<0><<<2048, 256, 0, stream>>>(m2b, nullptr, m2b, st1,
        msg_g2 + l * EMB, msg_be2 + l * EMB, (i64)NEDGES * EMB, 1.f / NEDGES);
    // aggr
    hipMemsetAsync(aggr, 0, (size_t)NATOMS * EMB * 4, stream);
    scatter_k<<<4096, 256, 0, stream>>>(m2b, dst, aggr, (i64)NEDGES * EMB);
    cvt_k<<<2048, 256, 0, stream>>>(aggr, aggrb, (i64)NATOMS * EMB);
    // u1
    mgemm_k<2, bf16><<<gN, 256, 0, stream>>>(h_bf, aggrb, nullptr, nullptr, Wt_u1[l],
        nullptr, nullptr, u1b, st2, NATOMS, 512, 256, 0);
    bnap_k<0><<<2048, 256, 0, stream>>>(u1b, nullptr, u1b, st2,
        upd_g1 + l * EMB, upd_be1 + l * EMB, (i64)NATOMS * EMB, 1.f / NATOMS);
    // u2
    mgemm_k<0, bf16><<<gN, 256, 0, stream>>>(u1b, nullptr, nullptr, nullptr, Wt_u2[l],
        nullptr, nullptr, u2b, st3, NATOMS, 256, 256, 0);
    // h = h + relu(bn(u2))
    bnap_k<1><<<2048, 256, 0, stream>>>(u2b, h_bf, h_bf, st3,
        upd_g2 + l * EMB, upd_be2 + l * EMB, (i64)NATOMS * EMB, 1.f / NATOMS);
  }

  // pool
  pool_seg_k<<<NB, 256, 0, stream>>>(h_bf, batch, g0b);

  // graph MLP + fp branch
  mgemm_k<0, bf16><<<dim3(8, 8), 256, 0, stream>>>(g0b, nullptr, nullptr, nullptr, Wt_gl1,
      gl_b1, nullptr, gh1b, nullptr, NB, 256, 1024, 1);
  mgemm_k<0, bf16><<<dim3(8, 8), 256, 0, stream>>>(gh1b, nullptr, nullptr, nullptr, Wt_gl2,
      gl_b2, nullptr, gh2b, nullptr, NB, 1024, 1024, 1);
  mgemm_k<0, float><<<dim3(4, 8), 256, 0, stream>>>(gh2b, nullptr, nullptr, nullptr, Wt_gl3,
      gl_b3, nullptr, g3, nullptr, NB, 1024, 512, 0);
  cvt_k<<<512, 256, 0, stream>>>(g3, g3b, (i64)NB * HIDF);
  cvt_k<<<512, 256, 0, stream>>>(fp, fpb, (i64)NB * 2048);
  mgemm_k<0, bf16><<<dim3(4, 8), 256, 0, stream>>>(fpb, nullptr, nullptr, nullptr, Wt_fp,
      fp_b, nullptr, fpfb, nullptr, NB, 2048, 512, 1);

  // attention 0: Q from fpf, K/V from g3; residual g3
  mgemm_k<0, float><<<dim3(4, 8), 256, 0, stream>>>(fpfb, nullptr, nullptr, nullptr, Wt_att[0],
      att_b + 0 * HIDF, nullptr, Qb, nullptr, NB, 512, 512, 0);
  mgemm_k<0, float><<<dim3(4, 8), 256, 0, stream>>>(g3b, nullptr, nullptr, nullptr, Wt_att[1],
      att_b + 1 * HIDF, nullptr, Kb, nullptr, NB, 512, 512, 0);
  mgemm_k<0, float><<<dim3(4, 8), 256, 0, stream>>>(g3b, nullptr, nullptr, nullptr, Wt_att[2],
      att_b + 2 * HIDF, nullptr, Vb, nullptr, NB, 512, 512, 0);
  attn_k<<<NB * NH, 64, 0, stream>>>(Qb, Kb, Vb, Obb);
  mgemm_k<0, float><<<dim3(4, 8), 256, 0, stream>>>(Obb, nullptr, nullptr, nullptr, Wt_att[3],
      att_b + 3 * HIDF, g3, gc1, nullptr, NB, 512, 512, 0);
  cvt_k<<<512, 256, 0, stream>>>(gc1, gc1b, (i64)NB * HIDF);

  // attention 1: self
  mgemm_k<0, float><<<dim3(4, 8), 256, 0, stream>>>(gc1b, nullptr, nullptr, nullptr, Wt_att[4],
      att_b + 4 * HIDF, nullptr, Qb, nullptr, NB, 512, 512, 0);
  mgemm_k<0, float><<<dim3(4, 8), 256, 0, stream>>>(gc1b, nullptr, nullptr, nullptr, Wt_att[5],
      att_b + 5 * HIDF, nullptr, Kb, nullptr, NB, 512, 512, 0);
  mgemm_k<0, float><<<dim3(4, 8), 256, 0, stream>>>(gc1b, nullptr, nullptr, nullptr, Wt_att[6],
      att_b + 6 * HIDF, nullptr, Vb, nullptr, NB, 512, 512, 0);
  attn_k<<<NB * NH, 64, 0, stream>>>(Qb, Kb, Vb, Obb);
  mgemm_k<0, float><<<dim3(4, 8), 256, 0, stream>>>(Obb, nullptr, nullptr, nullptr, Wt_att[7],
      att_b + 7 * HIDF, nullptr, gc2, nullptr, NB, 512, 512, 0);

  bind_loss_k<<<1, 256, 0, stream>>>(gc2, bind_w, bind_b, target, (float*)d_out);
}

// Round 5
// 2040.602 us; speedup vs baseline: 5.4065x; 1.0692x over previous
//
#include <hip/hip_runtime.h>
#include <hip/hip_bf16.h>
#include <math.h>

typedef long long i64;
typedef __hip_bfloat16 bf16;
typedef __attribute__((ext_vector_type(8))) short bfx8;
typedef __attribute__((ext_vector_type(4))) float f32x4;

#define NATOMS 60000
#define NEDGES 120000
#define NB     1024
#define EMB    256
#define NL     4
#define HIDF   512
#define NH     8
#define HD     64

__device__ __forceinline__ void storeT(float* p, float v) { *p = v; }
__device__ __forceinline__ void storeT(bf16* p, float v) { *p = __float2bfloat16(v); }

__device__ __forceinline__ void gl_lds16(const void* g, void* l) {
  __builtin_amdgcn_global_load_lds((const __attribute__((address_space(1))) void*)g,
                                   (__attribute__((address_space(3))) void*)l, 16, 0, 0);
}

// ================= MFMA GEMM: C = A @ Wt^T (+bias)(+resid)(relu?), fused BN stats =====
// A logical MxKp bf16 (Kp mult of 64, zero-padded); Wt is N x Kp bf16 (pre-transposed).
// MODE 0: A row-major MxKp.
// MODE 1: row r = concat(h[dst[r]](256), h[src[r]](256), ea_pad[r](64)), Kp=576.
// MODE 2: row r = concat(h[r](256), aggr[r](256)), Kp=512.
// Tile 128x128, BK=64, 4 waves (each 64x64 as 4x4 frags of 16x16x32).
// LDS layout: [r][64 bf16] with 16B-slot XOR swizzle (slot ^ (r&7)); staged via
// global_load_lds with inverse-swizzled global source (linear LDS dest).
template<int MODE, typename TO>
__global__ __launch_bounds__(256, 2) void mgemm_k(
    const bf16* __restrict__ A, const bf16* __restrict__ A2,
    const int* __restrict__ gdst, const int* __restrict__ gsrc,
    const bf16* __restrict__ Wt,
    const float* __restrict__ bias, const float* __restrict__ resid,
    TO* __restrict__ C, float* __restrict__ stats,
    int M, int Kp, int N, int doRelu)
{
  __shared__ short As[128 * 64];
  __shared__ short Bs[128 * 64];
  __shared__ float sSum[128], sSq[128];

  const int tid = threadIdx.x;
  const int w = tid >> 6, lane = tid & 63;
  const int wr = w >> 1, wc = w & 1;
  const int row0 = blockIdx.y * 128, col0 = blockIdx.x * 128;

  int rI[4], slotG[4], dIdx[4], sIdx[4], rClamp[4];
  #pragma unroll
  for (int i = 0; i < 4; ++i) {
    int lin = i * 256 + tid;
    int r = lin >> 3, sl = lin & 7;
    rI[i] = r;
    slotG[i] = sl ^ (r & 7);
    rClamp[i] = min(row0 + r, M - 1);
    if (MODE == 1) { dIdx[i] = gdst[rClamp[i]]; sIdx[i] = gsrc[rClamp[i]]; }
  }

  f32x4 acc[4][4];
  #pragma unroll
  for (int a = 0; a < 4; ++a)
    #pragma unroll
    for (int b = 0; b < 4; ++b)
      acc[a][b] = (f32x4){0.f, 0.f, 0.f, 0.f};

  const int KT = Kp >> 6;
  for (int kt = 0; kt < KT; ++kt) {
    const int k0 = kt << 6;
    // ---- stage A (4 x 16B per thread) ----
    #pragma unroll
    for (int i = 0; i < 4; ++i) {
      const bf16* g;
      int ko = slotG[i] * 8;
      if constexpr (MODE == 0) {
        g = A + (i64)rClamp[i] * Kp + k0 + ko;
      } else if constexpr (MODE == 1) {
        if (k0 < 256)      g = A  + (i64)dIdx[i] * EMB + k0 + ko;
        else if (k0 < 512) g = A  + (i64)sIdx[i] * EMB + (k0 - 256) + ko;
        else               g = A2 + (i64)rClamp[i] * 64 + (k0 - 512) + ko;
      } else {
        g = (k0 < 256) ? A  + (i64)rClamp[i] * EMB + k0 + ko
                       : A2 + (i64)rClamp[i] * EMB + (k0 - 256) + ko;
      }
      gl_lds16(g, (char*)&As[0] + i * 4096 + w * 1024);
    }
    // ---- stage B ----
    #pragma unroll
    for (int i = 0; i < 4; ++i) {
      const bf16* g = Wt + (i64)(col0 + rI[i]) * Kp + k0 + slotG[i] * 8;
      gl_lds16(g, (char*)&Bs[0] + i * 4096 + w * 1024);
    }
    __syncthreads();   // drains vmcnt before LDS use

    #pragma unroll
    for (int ks = 0; ks < 2; ++ks) {
      bfx8 af[4], bf_[4];
      #pragma unroll
      for (int mi = 0; mi < 4; ++mi) {
        int r = wr * 64 + mi * 16 + (lane & 15);
        int q = ks * 4 + (lane >> 4);
        int s = q ^ (r & 7);
        af[mi] = *(const bfx8*)&As[r * 64 + s * 8];
      }
      #pragma unroll
      for (int ni = 0; ni < 4; ++ni) {
        int n = wc * 64 + ni * 16 + (lane & 15);
        int q = ks * 4 + (lane >> 4);
        int s = q ^ (n & 7);
        bf_[ni] = *(const bfx8*)&Bs[n * 64 + s * 8];
      }
      #pragma unroll
      for (int mi = 0; mi < 4; ++mi)
        #pragma unroll
        for (int ni = 0; ni < 4; ++ni)
          acc[mi][ni] = __builtin_amdgcn_mfma_f32_16x16x32_bf16(af[mi], bf_[ni], acc[mi][ni], 0, 0, 0);
    }
    __syncthreads();
  }

  // ---- epilogue: C store (C/D layout: col = lane&15, row = (lane>>4)*4 + j) ----
  #pragma unroll
  for (int mi = 0; mi < 4; ++mi) {
    #pragma unroll
    for (int j = 0; j < 4; ++j) {
      int row = row0 + wr * 64 + mi * 16 + (lane >> 4) * 4 + j;
      if (row < M) {
        #pragma unroll
        for (int ni = 0; ni < 4; ++ni) {
          int col = col0 + wc * 64 + ni * 16 + (lane & 15);
          float v = acc[mi][ni][j];
          if (bias)  v += bias[col];
          if (resid) v += resid[(i64)row * N + col];
          if (doRelu) v = fmaxf(v, 0.f);
          storeT(&C[(i64)row * N + col], v);
        }
      }
    }
  }

  // ---- fused BN stats (sum, sumsq per column; N==256 layout [256 sum][256 sq]) ----
  if (stats) {
    if (tid < 128) { sSum[tid] = 0.f; sSq[tid] = 0.f; }
    __syncthreads();
    #pragma unroll
    for (int ni = 0; ni < 4; ++ni) {
      float ps = 0.f, pq = 0.f;
      #pragma unroll
      for (int mi = 0; mi < 4; ++mi)
        #pragma unroll
        for (int j = 0; j < 4; ++j) {
          int row = row0 + wr * 64 + mi * 16 + (lane >> 4) * 4 + j;
          if (row < M) { float v = acc[mi][ni][j]; ps += v; pq += v * v; }
        }
      ps += __shfl_xor(ps, 16); ps += __shfl_xor(ps, 32);
      pq += __shfl_xor(pq, 16); pq += __shfl_xor(pq, 32);
      if (lane < 16) {
        int c = wc * 64 + ni * 16 + lane;
        atomicAdd(&sSum[c], ps); atomicAdd(&sSq[c], pq);
      }
    }
    __syncthreads();
    if (tid < 128) {
      atomicAdd(&stats[col0 + tid], sSum[tid]);
      atomicAdd(&stats[256 + col0 + tid], sSq[tid]);
    }
  }
}

// ================= weight transpose+convert+pad: W f32 [K][N] -> Wt bf16 [N][Kp] ======
struct WDesc { const float* W; bf16* Wt; int K, N, Kp, bStart; };
struct WPack { WDesc d[29]; int cnt; };

__global__ __launch_bounds__(256) void wcvt_k(WPack p) {
  int bid = blockIdx.x;
  int di = 0;
  for (int i = 1; i < 29; ++i) if (i < p.cnt && bid >= p.d[i].bStart) di = i;
  WDesc wd = p.d[di];
  int t = bid - wd.bStart;
  int tilesN = wd.N >> 5;
  int tn = t % tilesN, tk = t / tilesN;
  __shared__ float tl[32][33];
  int tx = threadIdx.x & 31, ty = threadIdx.x >> 5;
  #pragma unroll
  for (int ii = 0; ii < 4; ++ii) {
    int k = tk * 32 + ty + ii * 8;
    int n = tn * 32 + tx;
    tl[ty + ii * 8][tx] = (k < wd.K) ? wd.W[(i64)k * wd.N + n] : 0.f;
  }
  __syncthreads();
  #pragma unroll
  for (int ii = 0; ii < 4; ++ii) {
    int n = tn * 32 + ty + ii * 8;
    int k = tk * 32 + tx;
    wd.Wt[(i64)n * wd.Kp + k] = __float2bfloat16(tl[tx][ty + ii * 8]);
  }
}

// ================= pad + convert f32 [rows][sc] -> bf16 [rows][dc], zero-pad ==========
__global__ void padcvt_k(const float* __restrict__ S, bf16* __restrict__ D,
                         int rows, int sc, int dc) {
  i64 total = (i64)rows * dc;
  for (i64 i = (i64)blockIdx.x * blockDim.x + threadIdx.x; i < total;
       i += (i64)gridDim.x * blockDim.x) {
    int r = (int)(i / dc), c = (int)(i % dc);
    D[i] = __float2bfloat16(c < sc ? S[(i64)r * sc + c] : 0.f);
  }
}

// ================= plain f32 -> bf16 convert ==========================================
__global__ void cvt_k(const float* __restrict__ S, bf16* __restrict__ D, i64 total) {
  i64 i0 = ((i64)blockIdx.x * blockDim.x + threadIdx.x) * 4;
  i64 stride = (i64)gridDim.x * blockDim.x * 4;
  for (i64 i = i0; i < total; i += stride) {
    float4 v = *(const float4*)(S + i);
    D[i + 0] = __float2bfloat16(v.x);
    D[i + 1] = __float2bfloat16(v.y);
    D[i + 2] = __float2bfloat16(v.z);
    D[i + 3] = __float2bfloat16(v.w);
  }
}

// ================= BN apply: Y = (add?h:0) + relu(gam*(X-mean)*rstd + bet), bf16 ======
template<int HASADD>
__global__ __launch_bounds__(256) void bnap_k(
    const bf16* __restrict__ X, const bf16* __restrict__ addIn, bf16* __restrict__ Y,
    const float* __restrict__ st, const float* __restrict__ gam, const float* __restrict__ bet,
    i64 total, float invM)
{
  __shared__ float sc[256], sh[256];
  {
    int c = threadIdx.x;
    float mean = st[c] * invM;
    float var  = st[256 + c] * invM - mean * mean;
    float rs   = rsqrtf(var + 1e-5f);
    float s    = gam[c] * rs;
    sc[c] = s; sh[c] = bet[c] - mean * s;
  }
  __syncthreads();
  i64 i0 = ((i64)blockIdx.x * blockDim.x + threadIdx.x) * 8;
  i64 stride = (i64)gridDim.x * blockDim.x * 8;
  for (i64 i = i0; i < total; i += stride) {
    bfx8 xv = *(const bfx8*)((const short*)X + i);
    bfx8 av;
    if (HASADD) av = *(const bfx8*)((const short*)addIn + i);
    int c0 = (int)(i & 255);
    bfx8 o;
    #pragma unroll
    for (int j = 0; j < 8; ++j) {
      unsigned short u = (unsigned short)xv[j];
      float x = __bfloat162float(*reinterpret_cast<const bf16*>(&u));
      int c = c0 + j;
      float t = fmaxf(x * sc[c] + sh[c], 0.f);
      if (HASADD) {
        unsigned short ua = (unsigned short)av[j];
        t += __bfloat162float(*reinterpret_cast<const bf16*>(&ua));
      }
      bf16 b = __float2bfloat16(t);
      o[j] = (short)*reinterpret_cast<unsigned short*>(&b);
    }
    *(bfx8*)((short*)Y + i) = o;
  }
}

// ================= CSR build: degree count, scan, fill ================================
__global__ void deg_k(const int* __restrict__ dst, int* __restrict__ deg) {
  int e = blockIdx.x * blockDim.x + threadIdx.x;
  if (e < NEDGES) atomicAdd(&deg[dst[e]], 1);
}

__global__ __launch_bounds__(1024) void scan_k(const int* __restrict__ deg,
                                               int* __restrict__ starts,
                                               int* __restrict__ cursor) {
  __shared__ int sh[1024];
  __shared__ int roff;
  if (threadIdx.x == 0) roff = 0;
  __syncthreads();
  const int nch = (NATOMS + 1023) / 1024;
  for (int ch = 0; ch < nch; ++ch) {
    int i = ch * 1024 + threadIdx.x;
    int v = (i < NATOMS) ? deg[i] : 0;
    sh[threadIdx.x] = v;
    __syncthreads();
    for (int ofs = 1; ofs < 1024; ofs <<= 1) {
      int t = (threadIdx.x >= ofs) ? sh[threadIdx.x - ofs] : 0;
      __syncthreads();
      sh[threadIdx.x] += t;
      __syncthreads();
    }
    int incl = sh[threadIdx.x];
    int base = roff;
    if (i < NATOMS) { int st = base + incl - v; starts[i] = st; cursor[i] = st; }
    __syncthreads();
    if (threadIdx.x == 1023) roff = base + sh[1023];
    __syncthreads();
  }
  if (threadIdx.x == 0) starts[NATOMS] = NEDGES;
}

__global__ void fill_k(const int* __restrict__ dst, int* __restrict__ cursor,
                       int* __restrict__ elist) {
  int e = blockIdx.x * blockDim.x + threadIdx.x;
  if (e < NEDGES) { int pos = atomicAdd(&cursor[dst[e]], 1); elist[pos] = e; }
}

// ================= fused BN(m2)+relu + CSR gather aggregation -> aggr bf16 ============
__global__ __launch_bounds__(256) void gather_k(
    const bf16* __restrict__ m2, const int* __restrict__ starts,
    const int* __restrict__ elist,
    const float* __restrict__ st, const float* __restrict__ gam,
    const float* __restrict__ bet, float invM, bf16* __restrict__ aggrb)
{
  const int c = threadIdx.x;
  float mean = st[c] * invM;
  float var  = st[256 + c] * invM - mean * mean;
  float rs   = rsqrtf(var + 1e-5f);
  float scv  = gam[c] * rs;
  float shv  = bet[c] - mean * scv;
  for (int n = blockIdx.x; n < NATOMS; n += gridDim.x) {
    int s = starts[n], e = starts[n + 1];
    float acc = 0.f;
    for (int i = s; i < e; ++i) {
      int eid = elist[i];  // wave-uniform broadcast
      float v = __bfloat162float(m2[(i64)eid * EMB + c]);
      acc += fmaxf(v * scv + shv, 0.f);
    }
    aggrb[(i64)n * EMB + c] = __float2bfloat16(acc);
  }
}

// ================= per-graph mean pool (batch sorted; binary-search segment) ==========
__global__ __launch_bounds__(256) void pool_seg_k(const bf16* __restrict__ h,
                                                  const int* __restrict__ batch,
                                                  bf16* __restrict__ g0b) {
  int b = blockIdx.x, c = threadIdx.x;
  int lo = 0, hi = NATOMS;
  while (lo < hi) { int mid = (lo + hi) >> 1; if (batch[mid] < b) lo = mid + 1; else hi = mid; }
  int s = lo;
  hi = NATOMS;
  while (lo < hi) { int mid = (lo + hi) >> 1; if (batch[mid] < b + 1) lo = mid + 1; else hi = mid; }
  int e = lo;
  float acc = 0.f;
  for (int r = s; r < e; ++r) acc += __bfloat162float(h[(i64)r * EMB + c]);
  g0b[b * EMB + c] = __float2bfloat16(acc / (float)max(e - s, 1));
}

// ================= attention core: per (b,head) outer-product softmax =================
__global__ __launch_bounds__(64) void attn_k(const float* __restrict__ Q, const float* __restrict__ K,
                                             const float* __restrict__ V, bf16* __restrict__ O) {
  int b = blockIdx.x >> 3, hh = blockIdx.x & 7;
  int d = threadIdx.x;
  __shared__ float Ks[HD], Vs[HD];
  Ks[d] = K[(i64)b * HIDF + hh * HD + d];
  Vs[d] = V[(i64)b * HIDF + hh * HD + d];
  __syncthreads();
  float q = Q[(i64)b * HIDF + hh * HD + d] * 0.125f;
  float mx = -1e30f;
  #pragma unroll
  for (int e = 0; e < HD; ++e) mx = fmaxf(mx, q * Ks[e]);
  float s = 0.f, o = 0.f;
  #pragma unroll
  for (int e = 0; e < HD; ++e) {
    float p = expf(q * Ks[e] - mx);
    s += p; o += p * Vs[e];
  }
  O[(i64)b * HIDF + d * NH + hh] = __float2bfloat16(o / s);  // (head_dim, head) flatten
}

// ================= bind head + BCE loss + sigmoid =====================================
__global__ __launch_bounds__(256) void bind_loss_k(const float* __restrict__ g, const float* __restrict__ W,
                                                   const float* __restrict__ bb, const float* __restrict__ tgt,
                                                   float* __restrict__ out) {
  int tid = threadIdx.x;
  float lsum = 0.f;
  for (int r = tid; r < NB; r += 256) {
    float a0 = bb[0], a1 = bb[1], a2 = bb[2];
    const float* gr = g + (i64)r * HIDF;
    for (int k = 0; k < HIDF; ++k) {
      float gv = gr[k];
      a0 += gv * W[k * 3 + 0];
      a1 += gv * W[k * 3 + 1];
      a2 += gv * W[k * 3 + 2];
    }
    float bv[3] = {a0, a1, a2};
    #pragma unroll
    for (int j = 0; j < 3; ++j) {
      float xv = bv[j], t = tgt[r * 3 + j];
      lsum += fmaxf(xv, 0.f) - xv * t + log1pf(expf(-fabsf(xv)));
      out[1 + r * 3 + j] = 1.f / (1.f + expf(-xv));
    }
  }
  __shared__ float red[256];
  red[tid] = lsum;
  __syncthreads();
  for (int s = 128; s > 0; s >>= 1) {
    if (tid < s) red[tid] += red[tid + s];
    __syncthreads();
  }
  if (tid == 0) out[0] = red[0] / (float)(NB * 3);
}

// ======================================================================================
extern "C" void kernel_launch(void* const* d_in, const int* in_sizes, int n_in,
                              void* d_out, int out_size, void* d_ws, size_t ws_size,
                              hipStream_t stream) {
  const float* x         = (const float*)d_in[0];
  const int*   ei        = (const int*)  d_in[1];
  const float* edge_attr = (const float*)d_in[2];
  const int*   batch     = (const int*)  d_in[3];
  const float* fp        = (const float*)d_in[4];
  const float* target    = (const float*)d_in[5];
  const float* lin_w     = (const float*)d_in[6];
  const float* lin_b     = (const float*)d_in[7];
  const float* msg_w1    = (const float*)d_in[8];
  const float* msg_g1    = (const float*)d_in[10];
  const float* msg_be1   = (const float*)d_in[11];
  const float* msg_w2    = (const float*)d_in[12];
  const float* msg_g2    = (const float*)d_in[14];
  const float* msg_be2   = (const float*)d_in[15];
  const float* upd_w1    = (const float*)d_in[16];
  const float* upd_g1    = (const float*)d_in[18];
  const float* upd_be1   = (const float*)d_in[19];
  const float* upd_w2    = (const float*)d_in[20];
  const float* upd_g2    = (const float*)d_in[22];
  const float* upd_be2   = (const float*)d_in[23];
  const float* gl_w1     = (const float*)d_in[24];
  const float* gl_b1     = (const float*)d_in[25];
  const float* gl_w2     = (const float*)d_in[26];
  const float* gl_b2     = (const float*)d_in[27];
  const float* gl_w3     = (const float*)d_in[28];
  const float* gl_b3     = (const float*)d_in[29];
  const float* fp_w      = (const float*)d_in[30];
  const float* fp_b      = (const float*)d_in[31];
  const float* att_w     = (const float*)d_in[32];
  const float* att_b     = (const float*)d_in[33];
  const float* bind_w    = (const float*)d_in[34];
  const float* bind_b    = (const float*)d_in[35];

  const int* src = ei;            // row 0 = source j
  const int* dst = ei + NEDGES;   // row 1 = target i

  // ---- workspace layout (total ~183.5 MB, < proven-safe 184.35 MB) ----
  char* base = (char*)d_ws;
  float* stats = (float*)base;                                   // 8192 f32 (16 slots x 512)
  char* p = base + 8192 * 4;
  int* deg    = (int*)p; p += 60000 * 4;                         // CSR degree (zeroed w/ stats)
  int* starts = (int*)p; p += 60004 * 4;
  int* cursor = (int*)p; p += 60000 * 4;
  int* elist  = (int*)p; p += 120000 * 4;
  bf16* h_bf  = (bf16*)p; p += (i64)NATOMS * EMB * 2;            // 30.72 MB
  bf16* ea_bf = (bf16*)p; p += (i64)NEDGES * 64 * 2;             // 15.36 MB
  bf16* wt    = (bf16*)p; p += 6651904LL * 2;                    // 13.3 MB weight pool
  char* R1 = p; p += 61440000LL;                                 // 61.44 MB
  char* R2 = p;                                                  // 61.44 MB

  // weight pool carve
  bf16* Wt_lin = wt; wt += 256 * 128;
  bf16 *Wt_m1[NL], *Wt_m2[NL], *Wt_u1[NL], *Wt_u2[NL];
  for (int l = 0; l < NL; ++l) { Wt_m1[l] = wt; wt += 256 * 576; }
  for (int l = 0; l < NL; ++l) { Wt_m2[l] = wt; wt += 256 * 256; }
  for (int l = 0; l < NL; ++l) { Wt_u1[l] = wt; wt += 256 * 512; }
  for (int l = 0; l < NL; ++l) { Wt_u2[l] = wt; wt += 256 * 256; }
  bf16* Wt_gl1 = wt; wt += 1024 * 256;
  bf16* Wt_gl2 = wt; wt += 1024 * 1024;
  bf16* Wt_gl3 = wt; wt += 512 * 1024;
  bf16* Wt_fp  = wt; wt += 512 * 2048;
  bf16* Wt_att[8];
  for (int i = 0; i < 8; ++i) { Wt_att[i] = wt; wt += 512 * 512; }

  // region aliases (ping-pong through the MPNN)
  bf16*  x_bf  = (bf16*)R2;         // 60000x128 (dead after lin GEMM)
  bf16*  m1b   = (bf16*)R1;         // E x 256
  bf16*  m2b   = (bf16*)R2;         // E x 256
  bf16*  aggrb = (bf16*)R1;         // N x 256 (m1b dead)
  bf16*  u1b   = (bf16*)R2;         // N x 256 (m2b dead after gather)
  bf16*  u2b   = (bf16*)R1;         // N x 256 (aggrb dead)

  // head scratch overlays R1 (MPNN edge buffers dead)
  bf16*  g0b  = (bf16*)R1;
  bf16*  gh1b = g0b + (i64)NB * EMB;
  bf16*  gh2b = gh1b + (i64)NB * 1024;
  float* g3   = (float*)(gh2b + (i64)NB * 1024);
  bf16*  g3b  = (bf16*)(g3 + (i64)NB * HIDF);
  bf16*  fpb  = g3b + (i64)NB * HIDF;
  bf16*  fpfb = fpb + (i64)NB * 2048;
  float* Qb   = (float*)(fpfb + (i64)NB * HIDF);
  float* Kb   = Qb + (i64)NB * HIDF;
  float* Vb   = Kb + (i64)NB * HIDF;
  bf16*  Obb  = (bf16*)(Vb + (i64)NB * HIDF);
  float* gc1  = (float*)(Obb + (i64)NB * HIDF);
  bf16*  gc1b = (bf16*)(gc1 + (i64)NB * HIDF);
  float* gc2  = (float*)(gc1b + (i64)NB * HIDF);

  // zero stats + deg in one memset (adjacent)
  hipMemsetAsync(stats, 0, (8192 + 60000) * 4, stream);

  // ---- CSR build (dst constant across layers; once per call) ----
  deg_k<<<(NEDGES + 255) / 256, 256, 0, stream>>>(dst, deg);
  scan_k<<<1, 1024, 0, stream>>>(deg, starts, cursor);
  fill_k<<<(NEDGES + 255) / 256, 256, 0, stream>>>(dst, cursor, elist);

  // ---- weight convert (one batched launch) ----
  WPack pk; int bs = 0, di = 0;
  auto addW = [&](const float* Wp, bf16* Wtp, int K, int N, int Kp) {
    pk.d[di].W = Wp; pk.d[di].Wt = Wtp; pk.d[di].K = K; pk.d[di].N = N;
    pk.d[di].Kp = Kp; pk.d[di].bStart = bs;
    bs += (Kp / 32) * (N / 32); ++di;
  };
  addW(lin_w, Wt_lin, 88, 256, 128);
  for (int l = 0; l < NL; ++l) addW(msg_w1 + (i64)l * 544 * 256, Wt_m1[l], 544, 256, 576);
  for (int l = 0; l < NL; ++l) addW(msg_w2 + (i64)l * 256 * 256, Wt_m2[l], 256, 256, 256);
  for (int l = 0; l < NL; ++l) addW(upd_w1 + (i64)l * 512 * 256, Wt_u1[l], 512, 256, 512);
  for (int l = 0; l < NL; ++l) addW(upd_w2 + (i64)l * 256 * 256, Wt_u2[l], 256, 256, 256);
  addW(gl_w1, Wt_gl1, 256, 1024, 256);
  addW(gl_w2, Wt_gl2, 1024, 1024, 1024);
  addW(gl_w3, Wt_gl3, 1024, 512, 1024);
  addW(fp_w, Wt_fp, 2048, 512, 2048);
  for (int i = 0; i < 8; ++i) addW(att_w + (i64)i * 512 * 512, Wt_att[i], 512, 512, 512);
  pk.cnt = di;
  wcvt_k<<<bs, 256, 0, stream>>>(pk);

  padcvt_k<<<2048, 256, 0, stream>>>(x, x_bf, NATOMS, 88, 128);
  padcvt_k<<<2048, 256, 0, stream>>>(edge_attr, ea_bf, NEDGES, 32, 64);

  dim3 gE(2, (NEDGES + 127) / 128), gN(2, (NATOMS + 127) / 128);

  // h = x @ lin_w + lin_b
  mgemm_k<0, bf16><<<gN, 256, 0, stream>>>(x_bf, nullptr, nullptr, nullptr, Wt_lin,
      lin_b, nullptr, h_bf, nullptr, NATOMS, 128, 256, 0);

  for (int l = 0; l < NL; ++l) {
    float* st0 = stats + (l * 4 + 0) * 512;
    float* st1 = stats + (l * 4 + 1) * 512;
    float* st2 = stats + (l * 4 + 2) * 512;
    float* st3 = stats + (l * 4 + 3) * 512;
    // m1 = concat(h[dst], h[src], ea) @ w1 (bias cancels through BN)
    mgemm_k<1, bf16><<<gE, 256, 0, stream>>>(h_bf, ea_bf, dst, src, Wt_m1[l],
        nullptr, nullptr, m1b, st0, NEDGES, 576, 256, 0);
    bnap_k<0><<<2048, 256, 0, stream>>>(m1b, nullptr, m1b, st0,
        msg_g1 + l * EMB, msg_be1 + l * EMB, (i64)NEDGES * EMB, 1.f / NEDGES);
    // m2 raw (stats fused); BN-apply deferred into gather
    mgemm_k<0, bf16><<<gE, 256, 0, stream>>>(m1b, nullptr, nullptr, nullptr, Wt_m2[l],
        nullptr, nullptr, m2b, st1, NEDGES, 256, 256, 0);
    // aggr[n] = sum_{e: dst=n} relu(bn(m2[e]))  — CSR gather, no atomics
    gather_k<<<2048, 256, 0, stream>>>(m2b, starts, elist, st1,
        msg_g2 + l * EMB, msg_be2 + l * EMB, 1.f / NEDGES, aggrb);
    // u1 = concat(h, aggr) @ uw1
    mgemm_k<2, bf16><<<gN, 256, 0, stream>>>(h_bf, aggrb, nullptr, nullptr, Wt_u1[l],
        nullptr, nullptr, u1b, st2, NATOMS, 512, 256, 0);
    bnap_k<0><<<2048, 256, 0, stream>>>(u1b, nullptr, u1b, st2,
        upd_g1 + l * EMB, upd_be1 + l * EMB, (i64)NATOMS * EMB, 1.f / NATOMS);
    // u2
    mgemm_k<0, bf16><<<gN, 256, 0, stream>>>(u1b, nullptr, nullptr, nullptr, Wt_u2[l],
        nullptr, nullptr, u2b, st3, NATOMS, 256, 256, 0);
    // h = h + relu(bn(u2))
    bnap_k<1><<<2048, 256, 0, stream>>>(u2b, h_bf, h_bf, st3,
        upd_g2 + l * EMB, upd_be2 + l * EMB, (i64)NATOMS * EMB, 1.f / NATOMS);
  }

  // pool
  pool_seg_k<<<NB, 256, 0, stream>>>(h_bf, batch, g0b);

  // graph MLP + fp branch
  mgemm_k<0, bf16><<<dim3(8, 8), 256, 0, stream>>>(g0b, nullptr, nullptr, nullptr, Wt_gl1,
      gl_b1, nullptr, gh1b, nullptr, NB, 256, 1024, 1);
  mgemm_k<0, bf16><<<dim3(8, 8), 256, 0, stream>>>(gh1b, nullptr, nullptr, nullptr, Wt_gl2,
      gl_b2, nullptr, gh2b, nullptr, NB, 1024, 1024, 1);
  mgemm_k<0, float><<<dim3(4, 8), 256, 0, stream>>>(gh2b, nullptr, nullptr, nullptr, Wt_gl3,
      gl_b3, nullptr, g3, nullptr, NB, 1024, 512, 0);
  cvt_k<<<512, 256, 0, stream>>>(g3, g3b, (i64)NB * HIDF);
  cvt_k<<<512, 256, 0, stream>>>(fp, fpb, (i64)NB * 2048);
  mgemm_k<0, bf16><<<dim3(4, 8), 256, 0, stream>>>(fpb, nullptr, nullptr, nullptr, Wt_fp,
      fp_b, nullptr, fpfb, nullptr, NB, 2048, 512, 1);

  // attention 0: Q from fpf, K/V from g3; residual g3
  mgemm_k<0, float><<<dim3(4, 8), 256, 0, stream>>>(fpfb, nullptr, nullptr, nullptr, Wt_att[0],
      att_b + 0 * HIDF, nullptr, Qb, nullptr, NB, 512, 512, 0);
  mgemm_k<0, float><<<dim3(4, 8), 256, 0, stream>>>(g3b, nullptr, nullptr, nullptr, Wt_att[1],
      att_b + 1 * HIDF, nullptr, Kb, nullptr, NB, 512, 512, 0);
  mgemm_k<0, float><<<dim3(4, 8), 256, 0, stream>>>(g3b, nullptr, nullptr, nullptr, Wt_att[2],
      att_b + 2 * HIDF, nullptr, Vb, nullptr, NB, 512, 512, 0);
  attn_k<<<NB * NH, 64, 0, stream>>>(Qb, Kb, Vb, Obb);
  mgemm_k<0, float><<<dim3(4, 8), 256, 0, stream>>>(Obb, nullptr, nullptr, nullptr, Wt_att[3],
      att_b + 3 * HIDF, g3, gc1, nullptr, NB, 512, 512, 0);
  cvt_k<<<512, 256, 0, stream>>>(gc1, gc1b, (i64)NB * HIDF);

  // attention 1: self
  mgemm_k<0, float><<<dim3(4, 8), 256, 0, stream>>>(gc1b, nullptr, nullptr, nullptr, Wt_att[4],
      att_b + 4 * HIDF, nullptr, Qb, nullptr, NB, 512, 512, 0);
  mgemm_k<0, float><<<dim3(4, 8), 256, 0, stream>>>(gc1b, nullptr, nullptr, nullptr, Wt_att[5],
      att_b + 5 * HIDF, nullptr, Kb, nullptr, NB, 512, 512, 0);
  mgemm_k<0, float><<<dim3(4, 8), 256, 0, stream>>>(gc1b, nullptr, nullptr, nullptr, Wt_att[6],
      att_b + 6 * HIDF, nullptr, Vb, nullptr, NB, 512, 512, 0);
  attn_k<<<NB * NH, 64, 0, stream>>>(Qb, Kb, Vb, Obb);
  mgemm_k<0, float><<<dim3(4, 8), 256, 0, stream>>>(Obb, nullptr, nullptr, nullptr, Wt_att[7],
      att_b + 7 * HIDF, nullptr, gc2, nullptr, NB, 512, 512, 0);

  bind_loss_k<<<1, 256, 0, stream>>>(gc2, bind_w, bind_b, target, (float*)d_out);
}

// Round 6
// 1860.507 us; speedup vs baseline: 5.9298x; 1.0968x over previous
//
#include <hip/hip_runtime.h>
#include <hip/hip_bf16.h>
#include <math.h>

typedef long long i64;
typedef __hip_bfloat16 bf16;
typedef __attribute__((ext_vector_type(8))) short bfx8;
typedef __attribute__((ext_vector_type(4))) float f32x4;

#define NATOMS 60000
#define NEDGES 120000
#define NB     1024
#define EMB    256
#define NL     4
#define HIDF   512
#define NH     8
#define HD     64
#define SCANB  235   // ceil(60000/256)

__device__ __forceinline__ void storeT(float* p, float v) { *p = v; }
__device__ __forceinline__ void storeT(bf16* p, float v) { *p = __float2bfloat16(v); }

__device__ __forceinline__ void gl_lds16(const void* g, void* l) {
  __builtin_amdgcn_global_load_lds((const __attribute__((address_space(1))) void*)g,
                                   (__attribute__((address_space(3))) void*)l, 16, 0, 0);
}

// ================= MFMA GEMM: C = A @ Wt^T (+bias)(+resid)(relu?), fused BN stats =====
// A logical MxKp bf16 (Kp mult of 64, zero-padded); Wt is N x Kp bf16 (pre-transposed).
// MODE 0: A row-major MxKp.
// MODE 1: row r = concat(h[dst[r]](256), h[src[r]](256), ea_pad[r](64)), Kp=576.
// MODE 2: row r = concat(h[r](256), aggr[r](256)), Kp=512.
// Tile 128x128, BK=64, 4 waves (each 64x64 as 4x4 frags of 16x16x32).
// LDS layout: [r][64 bf16] with 16B-slot XOR swizzle (slot ^ (r&7)); staged via
// global_load_lds with inverse-swizzled global source (linear LDS dest).
template<int MODE, typename TO>
__global__ __launch_bounds__(256, 2) void mgemm_k(
    const bf16* __restrict__ A, const bf16* __restrict__ A2,
    const int* __restrict__ gdst, const int* __restrict__ gsrc,
    const bf16* __restrict__ Wt,
    const float* __restrict__ bias, const float* __restrict__ resid,
    TO* __restrict__ C, float* __restrict__ stats,
    int M, int Kp, int N, int doRelu)
{
  __shared__ short As[128 * 64];
  __shared__ short Bs[128 * 64];
  __shared__ float sSum[128], sSq[128];

  const int tid = threadIdx.x;
  const int w = tid >> 6, lane = tid & 63;
  const int wr = w >> 1, wc = w & 1;
  const int row0 = blockIdx.y * 128, col0 = blockIdx.x * 128;

  int rI[4], slotG[4], dIdx[4], sIdx[4], rClamp[4];
  #pragma unroll
  for (int i = 0; i < 4; ++i) {
    int lin = i * 256 + tid;
    int r = lin >> 3, sl = lin & 7;
    rI[i] = r;
    slotG[i] = sl ^ (r & 7);
    rClamp[i] = min(row0 + r, M - 1);
    if (MODE == 1) { dIdx[i] = gdst[rClamp[i]]; sIdx[i] = gsrc[rClamp[i]]; }
  }

  f32x4 acc[4][4];
  #pragma unroll
  for (int a = 0; a < 4; ++a)
    #pragma unroll
    for (int b = 0; b < 4; ++b)
      acc[a][b] = (f32x4){0.f, 0.f, 0.f, 0.f};

  const int KT = Kp >> 6;
  for (int kt = 0; kt < KT; ++kt) {
    const int k0 = kt << 6;
    // ---- stage A (4 x 16B per thread) ----
    #pragma unroll
    for (int i = 0; i < 4; ++i) {
      const bf16* g;
      int ko = slotG[i] * 8;
      if constexpr (MODE == 0) {
        g = A + (i64)rClamp[i] * Kp + k0 + ko;
      } else if constexpr (MODE == 1) {
        if (k0 < 256)      g = A  + (i64)dIdx[i] * EMB + k0 + ko;
        else if (k0 < 512) g = A  + (i64)sIdx[i] * EMB + (k0 - 256) + ko;
        else               g = A2 + (i64)rClamp[i] * 64 + (k0 - 512) + ko;
      } else {
        g = (k0 < 256) ? A  + (i64)rClamp[i] * EMB + k0 + ko
                       : A2 + (i64)rClamp[i] * EMB + (k0 - 256) + ko;
      }
      gl_lds16(g, (char*)&As[0] + i * 4096 + w * 1024);
    }
    // ---- stage B ----
    #pragma unroll
    for (int i = 0; i < 4; ++i) {
      const bf16* g = Wt + (i64)(col0 + rI[i]) * Kp + k0 + slotG[i] * 8;
      gl_lds16(g, (char*)&Bs[0] + i * 4096 + w * 1024);
    }
    __syncthreads();   // drains vmcnt before LDS use

    #pragma unroll
    for (int ks = 0; ks < 2; ++ks) {
      bfx8 af[4], bf_[4];
      #pragma unroll
      for (int mi = 0; mi < 4; ++mi) {
        int r = wr * 64 + mi * 16 + (lane & 15);
        int q = ks * 4 + (lane >> 4);
        int s = q ^ (r & 7);
        af[mi] = *(const bfx8*)&As[r * 64 + s * 8];
      }
      #pragma unroll
      for (int ni = 0; ni < 4; ++ni) {
        int n = wc * 64 + ni * 16 + (lane & 15);
        int q = ks * 4 + (lane >> 4);
        int s = q ^ (n & 7);
        bf_[ni] = *(const bfx8*)&Bs[n * 64 + s * 8];
      }
      #pragma unroll
      for (int mi = 0; mi < 4; ++mi)
        #pragma unroll
        for (int ni = 0; ni < 4; ++ni)
          acc[mi][ni] = __builtin_amdgcn_mfma_f32_16x16x32_bf16(af[mi], bf_[ni], acc[mi][ni], 0, 0, 0);
    }
    __syncthreads();
  }

  // ---- epilogue: C store (C/D layout: col = lane&15, row = (lane>>4)*4 + j) ----
  #pragma unroll
  for (int mi = 0; mi < 4; ++mi) {
    #pragma unroll
    for (int j = 0; j < 4; ++j) {
      int row = row0 + wr * 64 + mi * 16 + (lane >> 4) * 4 + j;
      if (row < M) {
        #pragma unroll
        for (int ni = 0; ni < 4; ++ni) {
          int col = col0 + wc * 64 + ni * 16 + (lane & 15);
          float v = acc[mi][ni][j];
          if (bias)  v += bias[col];
          if (resid) v += resid[(i64)row * N + col];
          if (doRelu) v = fmaxf(v, 0.f);
          storeT(&C[(i64)row * N + col], v);
        }
      }
    }
  }

  // ---- fused BN stats (sum, sumsq per column; N==256 layout [256 sum][256 sq]) ----
  if (stats) {
    if (tid < 128) { sSum[tid] = 0.f; sSq[tid] = 0.f; }
    __syncthreads();
    #pragma unroll
    for (int ni = 0; ni < 4; ++ni) {
      float ps = 0.f, pq = 0.f;
      #pragma unroll
      for (int mi = 0; mi < 4; ++mi)
        #pragma unroll
        for (int j = 0; j < 4; ++j) {
          int row = row0 + wr * 64 + mi * 16 + (lane >> 4) * 4 + j;
          if (row < M) { float v = acc[mi][ni][j]; ps += v; pq += v * v; }
        }
      ps += __shfl_xor(ps, 16); ps += __shfl_xor(ps, 32);
      pq += __shfl_xor(pq, 16); pq += __shfl_xor(pq, 32);
      if (lane < 16) {
        int c = wc * 64 + ni * 16 + lane;
        atomicAdd(&sSum[c], ps); atomicAdd(&sSq[c], pq);
      }
    }
    __syncthreads();
    if (tid < 128) {
      atomicAdd(&stats[col0 + tid], sSum[tid]);
      atomicAdd(&stats[256 + col0 + tid], sSq[tid]);
    }
  }
}

// ================= weight transpose+convert+pad: W f32 [K][N] -> Wt bf16 [N][Kp] ======
struct WDesc { const float* W; bf16* Wt; int K, N, Kp, bStart; };
struct WPack { WDesc d[29]; int cnt; };

__global__ __launch_bounds__(256) void wcvt_k(WPack p) {
  int bid = blockIdx.x;
  int di = 0;
  for (int i = 1; i < 29; ++i) if (i < p.cnt && bid >= p.d[i].bStart) di = i;
  WDesc wd = p.d[di];
  int t = bid - wd.bStart;
  int tilesN = wd.N >> 5;
  int tn = t % tilesN, tk = t / tilesN;
  __shared__ float tl[32][33];
  int tx = threadIdx.x & 31, ty = threadIdx.x >> 5;
  #pragma unroll
  for (int ii = 0; ii < 4; ++ii) {
    int k = tk * 32 + ty + ii * 8;
    int n = tn * 32 + tx;
    tl[ty + ii * 8][tx] = (k < wd.K) ? wd.W[(i64)k * wd.N + n] : 0.f;
  }
  __syncthreads();
  #pragma unroll
  for (int ii = 0; ii < 4; ++ii) {
    int n = tn * 32 + ty + ii * 8;
    int k = tk * 32 + tx;
    wd.Wt[(i64)n * wd.Kp + k] = __float2bfloat16(tl[tx][ty + ii * 8]);
  }
}

// ================= pad + convert f32 [rows][sc] -> bf16 [rows][dc], zero-pad ==========
__global__ void padcvt_k(const float* __restrict__ S, bf16* __restrict__ D,
                         int rows, int sc, int dc) {
  i64 total = (i64)rows * dc;
  for (i64 i = (i64)blockIdx.x * blockDim.x + threadIdx.x; i < total;
       i += (i64)gridDim.x * blockDim.x) {
    int r = (int)(i / dc), c = (int)(i % dc);
    D[i] = __float2bfloat16(c < sc ? S[(i64)r * sc + c] : 0.f);
  }
}

// ================= plain f32 -> bf16 convert ==========================================
__global__ void cvt_k(const float* __restrict__ S, bf16* __restrict__ D, i64 total) {
  i64 i0 = ((i64)blockIdx.x * blockDim.x + threadIdx.x) * 4;
  i64 stride = (i64)gridDim.x * blockDim.x * 4;
  for (i64 i = i0; i < total; i += stride) {
    float4 v = *(const float4*)(S + i);
    D[i + 0] = __float2bfloat16(v.x);
    D[i + 1] = __float2bfloat16(v.y);
    D[i + 2] = __float2bfloat16(v.z);
    D[i + 3] = __float2bfloat16(v.w);
  }
}

// ================= BN apply: Y = (add?h:0) + relu(gam*(X-mean)*rstd + bet), bf16 ======
template<int HASADD>
__global__ __launch_bounds__(256) void bnap_k(
    const bf16* __restrict__ X, const bf16* __restrict__ addIn, bf16* __restrict__ Y,
    const float* __restrict__ st, const float* __restrict__ gam, const float* __restrict__ bet,
    i64 total, float invM)
{
  __shared__ float sc[256], sh[256];
  {
    int c = threadIdx.x;
    float mean = st[c] * invM;
    float var  = st[256 + c] * invM - mean * mean;
    float rs   = rsqrtf(var + 1e-5f);
    float s    = gam[c] * rs;
    sc[c] = s; sh[c] = bet[c] - mean * s;
  }
  __syncthreads();
  i64 i0 = ((i64)blockIdx.x * blockDim.x + threadIdx.x) * 8;
  i64 stride = (i64)gridDim.x * blockDim.x * 8;
  for (i64 i = i0; i < total; i += stride) {
    bfx8 xv = *(const bfx8*)((const short*)X + i);
    bfx8 av;
    if (HASADD) av = *(const bfx8*)((const short*)addIn + i);
    int c0 = (int)(i & 255);
    bfx8 o;
    #pragma unroll
    for (int j = 0; j < 8; ++j) {
      unsigned short u = (unsigned short)xv[j];
      float x = __bfloat162float(*reinterpret_cast<const bf16*>(&u));
      int c = c0 + j;
      float t = fmaxf(x * sc[c] + sh[c], 0.f);
      if (HASADD) {
        unsigned short ua = (unsigned short)av[j];
        t += __bfloat162float(*reinterpret_cast<const bf16*>(&ua));
      }
      bf16 b = __float2bfloat16(t);
      o[j] = (short)*reinterpret_cast<unsigned short*>(&b);
    }
    *(bfx8*)((short*)Y + i) = o;
  }
}

// ================= CSR build: degree count, 3-phase scan, fill ========================
__global__ void deg_k(const int* __restrict__ dst, int* __restrict__ deg) {
  int e = blockIdx.x * blockDim.x + threadIdx.x;
  if (e < NEDGES) atomicAdd(&deg[dst[e]], 1);
}

// phase A: per-block (256-elem chunk) sum -> bsum[SCANB]
__global__ __launch_bounds__(256) void scanA_k(const int* __restrict__ deg, int* __restrict__ bsum) {
  __shared__ int sh[256];
  int i = blockIdx.x * 256 + threadIdx.x;
  sh[threadIdx.x] = (i < NATOMS) ? deg[i] : 0;
  __syncthreads();
  for (int s = 128; s > 0; s >>= 1) {
    if (threadIdx.x < s) sh[threadIdx.x] += sh[threadIdx.x + s];
    __syncthreads();
  }
  if (threadIdx.x == 0) bsum[blockIdx.x] = sh[0];
}

// phase B: exclusive scan of bsum (SCANB<=256), single block
__global__ __launch_bounds__(256) void scanB_k(int* __restrict__ bsum) {
  __shared__ int sh[256];
  int v = (threadIdx.x < SCANB) ? bsum[threadIdx.x] : 0;
  sh[threadIdx.x] = v;
  __syncthreads();
  for (int ofs = 1; ofs < 256; ofs <<= 1) {
    int t = (threadIdx.x >= ofs) ? sh[threadIdx.x - ofs] : 0;
    __syncthreads();
    sh[threadIdx.x] += t;
    __syncthreads();
  }
  if (threadIdx.x < SCANB) bsum[threadIdx.x] = sh[threadIdx.x] - v;  // exclusive
}

// phase C: local inclusive scan + block offset -> starts, cursor
__global__ __launch_bounds__(256) void scanC_k(const int* __restrict__ deg,
                                               const int* __restrict__ bsum,
                                               int* __restrict__ starts,
                                               int* __restrict__ cursor) {
  __shared__ int sh[256];
  int i = blockIdx.x * 256 + threadIdx.x;
  int v = (i < NATOMS) ? deg[i] : 0;
  sh[threadIdx.x] = v;
  __syncthreads();
  for (int ofs = 1; ofs < 256; ofs <<= 1) {
    int t = (threadIdx.x >= ofs) ? sh[threadIdx.x - ofs] : 0;
    __syncthreads();
    sh[threadIdx.x] += t;
    __syncthreads();
  }
  int excl = bsum[blockIdx.x] + sh[threadIdx.x] - v;
  if (i < NATOMS) { starts[i] = excl; cursor[i] = excl; }
  if (i == NATOMS - 1) starts[NATOMS] = NEDGES;
}

__global__ void fill_k(const int* __restrict__ dst, int* __restrict__ cursor,
                       int* __restrict__ elist) {
  int e = blockIdx.x * blockDim.x + threadIdx.x;
  if (e < NEDGES) { int pos = atomicAdd(&cursor[dst[e]], 1); elist[pos] = e; }
}

// ================= fused BN(m2)+relu + CSR gather aggregation -> aggr bf16 ============
__global__ __launch_bounds__(256) void gather_k(
    const bf16* __restrict__ m2, const int* __restrict__ starts,
    const int* __restrict__ elist,
    const float* __restrict__ st, const float* __restrict__ gam,
    const float* __restrict__ bet, float invM, bf16* __restrict__ aggrb)
{
  const int c = threadIdx.x;
  float mean = st[c] * invM;
  float var  = st[256 + c] * invM - mean * mean;
  float rs   = rsqrtf(var + 1e-5f);
  float scv  = gam[c] * rs;
  float shv  = bet[c] - mean * scv;
  for (int n = blockIdx.x; n < NATOMS; n += gridDim.x) {
    int s = starts[n], e = starts[n + 1];
    float acc = 0.f;
    for (int i = s; i < e; ++i) {
      int eid = elist[i];  // wave-uniform broadcast
      float v = __bfloat162float(m2[(i64)eid * EMB + c]);
      acc += fmaxf(v * scv + shv, 0.f);
    }
    aggrb[(i64)n * EMB + c] = __float2bfloat16(acc);
  }
}

// ================= per-graph mean pool (batch sorted; binary-search segment) ==========
__global__ __launch_bounds__(256) void pool_seg_k(const bf16* __restrict__ h,
                                                  const int* __restrict__ batch,
                                                  bf16* __restrict__ g0b) {
  int b = blockIdx.x, c = threadIdx.x;
  int lo = 0, hi = NATOMS;
  while (lo < hi) { int mid = (lo + hi) >> 1; if (batch[mid] < b) lo = mid + 1; else hi = mid; }
  int s = lo;
  hi = NATOMS;
  while (lo < hi) { int mid = (lo + hi) >> 1; if (batch[mid] < b + 1) lo = mid + 1; else hi = mid; }
  int e = lo;
  float acc = 0.f;
  for (int r = s; r < e; ++r) acc += __bfloat162float(h[(i64)r * EMB + c]);
  g0b[b * EMB + c] = __float2bfloat16(acc / (float)max(e - s, 1));
}

// ================= attention core: per (b,head) outer-product softmax =================
__global__ __launch_bounds__(64) void attn_k(const float* __restrict__ Q, const float* __restrict__ K,
                                             const float* __restrict__ V, bf16* __restrict__ O) {
  int b = blockIdx.x >> 3, hh = blockIdx.x & 7;
  int d = threadIdx.x;
  __shared__ float Ks[HD], Vs[HD];
  Ks[d] = K[(i64)b * HIDF + hh * HD + d];
  Vs[d] = V[(i64)b * HIDF + hh * HD + d];
  __syncthreads();
  float q = Q[(i64)b * HIDF + hh * HD + d] * 0.125f;
  float mx = -1e30f;
  #pragma unroll
  for (int e = 0; e < HD; ++e) mx = fmaxf(mx, q * Ks[e]);
  float s = 0.f, o = 0.f;
  #pragma unroll
  for (int e = 0; e < HD; ++e) {
    float p = expf(q * Ks[e] - mx);
    s += p; o += p * Vs[e];
  }
  O[(i64)b * HIDF + d * NH + hh] = __float2bfloat16(o / s);  // (head_dim, head) flatten
}

// ================= bind head + BCE loss + sigmoid (parallel, 8 threads/row) ===========
// out[0] must be zeroed before launch; partial losses atomicAdd'ed.
__global__ __launch_bounds__(256) void bind_loss_k(const float* __restrict__ g, const float* __restrict__ W,
                                                   const float* __restrict__ bb, const float* __restrict__ tgt,
                                                   float* __restrict__ out) {
  int gt = blockIdx.x * 256 + threadIdx.x;
  int r = gt >> 3, sub = gt & 7;     // 8 threads per row, 32 blocks covers 1024 rows
  float a0 = 0.f, a1 = 0.f, a2 = 0.f;
  const float* gr = g + (i64)r * HIDF + sub * 64;
  for (int k = 0; k < 64; ++k) {
    float gv = gr[k];
    const float* wr_ = W + (sub * 64 + k) * 3;
    a0 += gv * wr_[0];
    a1 += gv * wr_[1];
    a2 += gv * wr_[2];
  }
  #pragma unroll
  for (int ofs = 4; ofs > 0; ofs >>= 1) {
    a0 += __shfl_down(a0, ofs, 8);
    a1 += __shfl_down(a1, ofs, 8);
    a2 += __shfl_down(a2, ofs, 8);
  }
  float lsum = 0.f;
  if (sub == 0) {
    float bv[3] = {a0 + bb[0], a1 + bb[1], a2 + bb[2]};
    #pragma unroll
    for (int j = 0; j < 3; ++j) {
      float xv = bv[j], t = tgt[r * 3 + j];
      lsum += fmaxf(xv, 0.f) - xv * t + log1pf(expf(-fabsf(xv)));
      out[1 + r * 3 + j] = 1.f / (1.f + expf(-xv));
    }
  }
  __shared__ float red[256];
  red[threadIdx.x] = lsum;
  __syncthreads();
  for (int s = 128; s > 0; s >>= 1) {
    if (threadIdx.x < s) red[threadIdx.x] += red[threadIdx.x + s];
    __syncthreads();
  }
  if (threadIdx.x == 0) atomicAdd(&out[0], red[0] * (1.f / (NB * 3)));
}

// ======================================================================================
extern "C" void kernel_launch(void* const* d_in, const int* in_sizes, int n_in,
                              void* d_out, int out_size, void* d_ws, size_t ws_size,
                              hipStream_t stream) {
  const float* x         = (const float*)d_in[0];
  const int*   ei        = (const int*)  d_in[1];
  const float* edge_attr = (const float*)d_in[2];
  const int*   batch     = (const int*)  d_in[3];
  const float* fp        = (const float*)d_in[4];
  const float* target    = (const float*)d_in[5];
  const float* lin_w     = (const float*)d_in[6];
  const float* lin_b     = (const float*)d_in[7];
  const float* msg_w1    = (const float*)d_in[8];
  const float* msg_g1    = (const float*)d_in[10];
  const float* msg_be1   = (const float*)d_in[11];
  const float* msg_w2    = (const float*)d_in[12];
  const float* msg_g2    = (const float*)d_in[14];
  const float* msg_be2   = (const float*)d_in[15];
  const float* upd_w1    = (const float*)d_in[16];
  const float* upd_g1    = (const float*)d_in[18];
  const float* upd_be1   = (const float*)d_in[19];
  const float* upd_w2    = (const float*)d_in[20];
  const float* upd_g2    = (const float*)d_in[22];
  const float* upd_be2   = (const float*)d_in[23];
  const float* gl_w1     = (const float*)d_in[24];
  const float* gl_b1     = (const float*)d_in[25];
  const float* gl_w2     = (const float*)d_in[26];
  const float* gl_b2     = (const float*)d_in[27];
  const float* gl_w3     = (const float*)d_in[28];
  const float* gl_b3     = (const float*)d_in[29];
  const float* fp_w      = (const float*)d_in[30];
  const float* fp_b      = (const float*)d_in[31];
  const float* att_w     = (const float*)d_in[32];
  const float* att_b     = (const float*)d_in[33];
  const float* bind_w    = (const float*)d_in[34];
  const float* bind_b    = (const float*)d_in[35];

  const int* src = ei;            // row 0 = source j
  const int* dst = ei + NEDGES;   // row 1 = target i

  // ---- workspace layout (total ~183.5 MB, < proven-safe 184.35 MB) ----
  char* base = (char*)d_ws;
  float* stats = (float*)base;                                   // 8192 f32 (16 slots x 512)
  char* p = base + 8192 * 4;
  int* deg    = (int*)p; p += 60000 * 4;                         // CSR degree (zeroed w/ stats)
  int* starts = (int*)p; p += 60004 * 4;
  int* cursor = (int*)p; p += 60000 * 4;
  int* elist  = (int*)p; p += 120000 * 4;
  int* bsum   = (int*)p; p += 256 * 4;
  bf16* h_bf  = (bf16*)p; p += (i64)NATOMS * EMB * 2;            // 30.72 MB
  bf16* ea_bf = (bf16*)p; p += (i64)NEDGES * 64 * 2;             // 15.36 MB
  bf16* wt    = (bf16*)p; p += 6651904LL * 2;                    // 13.3 MB weight pool
  char* R1 = p; p += 61440000LL;                                 // 61.44 MB
  char* R2 = p;                                                  // 61.44 MB

  // weight pool carve
  bf16* Wt_lin = wt; wt += 256 * 128;
  bf16 *Wt_m1[NL], *Wt_m2[NL], *Wt_u1[NL], *Wt_u2[NL];
  for (int l = 0; l < NL; ++l) { Wt_m1[l] = wt; wt += 256 * 576; }
  for (int l = 0; l < NL; ++l) { Wt_m2[l] = wt; wt += 256 * 256; }
  for (int l = 0; l < NL; ++l) { Wt_u1[l] = wt; wt += 256 * 512; }
  for (int l = 0; l < NL; ++l) { Wt_u2[l] = wt; wt += 256 * 256; }
  bf16* Wt_gl1 = wt; wt += 1024 * 256;
  bf16* Wt_gl2 = wt; wt += 1024 * 1024;
  bf16* Wt_gl3 = wt; wt += 512 * 1024;
  bf16* Wt_fp  = wt; wt += 512 * 2048;
  bf16* Wt_att[8];
  for (int i = 0; i < 8; ++i) { Wt_att[i] = wt; wt += 512 * 512; }

  // region aliases (ping-pong through the MPNN)
  bf16*  x_bf  = (bf16*)R2;         // 60000x128 (dead after lin GEMM)
  bf16*  m1b   = (bf16*)R1;         // E x 256
  bf16*  m2b   = (bf16*)R2;         // E x 256
  bf16*  aggrb = (bf16*)R1;         // N x 256 (m1b dead)
  bf16*  u1b   = (bf16*)R2;         // N x 256 (m2b dead after gather)
  bf16*  u2b   = (bf16*)R1;         // N x 256 (aggrb dead)

  // head scratch overlays R1 (MPNN edge buffers dead)
  bf16*  g0b  = (bf16*)R1;
  bf16*  gh1b = g0b + (i64)NB * EMB;
  bf16*  gh2b = gh1b + (i64)NB * 1024;
  float* g3   = (float*)(gh2b + (i64)NB * 1024);
  bf16*  g3b  = (bf16*)(g3 + (i64)NB * HIDF);
  bf16*  fpb  = g3b + (i64)NB * HIDF;
  bf16*  fpfb = fpb + (i64)NB * 2048;
  float* Qb   = (float*)(fpfb + (i64)NB * HIDF);
  float* Kb   = Qb + (i64)NB * HIDF;
  float* Vb   = Kb + (i64)NB * HIDF;
  bf16*  Obb  = (bf16*)(Vb + (i64)NB * HIDF);
  float* gc1  = (float*)(Obb + (i64)NB * HIDF);
  bf16*  gc1b = (bf16*)(gc1 + (i64)NB * HIDF);
  float* gc2  = (float*)(gc1b + (i64)NB * HIDF);

  // zero stats + deg in one memset (adjacent); zero out[0] for loss atomics
  hipMemsetAsync(stats, 0, (8192 + 60000) * 4, stream);
  hipMemsetAsync(d_out, 0, 4, stream);

  // ---- CSR build (dst constant across layers; once per call) ----
  deg_k<<<(NEDGES + 255) / 256, 256, 0, stream>>>(dst, deg);
  scanA_k<<<SCANB, 256, 0, stream>>>(deg, bsum);
  scanB_k<<<1, 256, 0, stream>>>(bsum);
  scanC_k<<<SCANB, 256, 0, stream>>>(deg, bsum, starts, cursor);
  fill_k<<<(NEDGES + 255) / 256, 256, 0, stream>>>(dst, cursor, elist);

  // ---- weight convert (one batched launch) ----
  WPack pk; int bs = 0, di = 0;
  auto addW = [&](const float* Wp, bf16* Wtp, int K, int N, int Kp) {
    pk.d[di].W = Wp; pk.d[di].Wt = Wtp; pk.d[di].K = K; pk.d[di].N = N;
    pk.d[di].Kp = Kp; pk.d[di].bStart = bs;
    bs += (Kp / 32) * (N / 32); ++di;
  };
  addW(lin_w, Wt_lin, 88, 256, 128);
  for (int l = 0; l < NL; ++l) addW(msg_w1 + (i64)l * 544 * 256, Wt_m1[l], 544, 256, 576);
  for (int l = 0; l < NL; ++l) addW(msg_w2 + (i64)l * 256 * 256, Wt_m2[l], 256, 256, 256);
  for (int l = 0; l < NL; ++l) addW(upd_w1 + (i64)l * 512 * 256, Wt_u1[l], 512, 256, 512);
  for (int l = 0; l < NL; ++l) addW(upd_w2 + (i64)l * 256 * 256, Wt_u2[l], 256, 256, 256);
  addW(gl_w1, Wt_gl1, 256, 1024, 256);
  addW(gl_w2, Wt_gl2, 1024, 1024, 1024);
  addW(gl_w3, Wt_gl3, 1024, 512, 1024);
  addW(fp_w, Wt_fp, 2048, 512, 2048);
  for (int i = 0; i < 8; ++i) addW(att_w + (i64)i * 512 * 512, Wt_att[i], 512, 512, 512);
  pk.cnt = di;
  wcvt_k<<<bs, 256, 0, stream>>>(pk);

  padcvt_k<<<2048, 256, 0, stream>>>(x, x_bf, NATOMS, 88, 128);
  padcvt_k<<<2048, 256, 0, stream>>>(edge_attr, ea_bf, NEDGES, 32, 64);

  dim3 gE(2, (NEDGES + 127) / 128), gN(2, (NATOMS + 127) / 128);

  // h = x @ lin_w + lin_b
  mgemm_k<0, bf16><<<gN, 256, 0, stream>>>(x_bf, nullptr, nullptr, nullptr, Wt_lin,
      lin_b, nullptr, h_bf, nullptr, NATOMS, 128, 256, 0);

  for (int l = 0; l < NL; ++l) {
    float* st0 = stats + (l * 4 + 0) * 512;
    float* st1 = stats + (l * 4 + 1) * 512;
    float* st2 = stats + (l * 4 + 2) * 512;
    float* st3 = stats + (l * 4 + 3) * 512;
    // m1 = concat(h[dst], h[src], ea) @ w1 (bias cancels through BN)
    mgemm_k<1, bf16><<<gE, 256, 0, stream>>>(h_bf, ea_bf, dst, src, Wt_m1[l],
        nullptr, nullptr, m1b, st0, NEDGES, 576, 256, 0);
    bnap_k<0><<<2048, 256, 0, stream>>>(m1b, nullptr, m1b, st0,
        msg_g1 + l * EMB, msg_be1 + l * EMB, (i64)NEDGES * EMB, 1.f / NEDGES);
    // m2 raw (stats fused); BN-apply deferred into gather
    mgemm_k<0, bf16><<<gE, 256, 0, stream>>>(m1b, nullptr, nullptr, nullptr, Wt_m2[l],
        nullptr, nullptr, m2b, st1, NEDGES, 256, 256, 0);
    // aggr[n] = sum_{e: dst=n} relu(bn(m2[e]))  — CSR gather, no atomics
    gather_k<<<2048, 256, 0, stream>>>(m2b, starts, elist, st1,
        msg_g2 + l * EMB, msg_be2 + l * EMB, 1.f / NEDGES, aggrb);
    // u1 = concat(h, aggr) @ uw1
    mgemm_k<2, bf16><<<gN, 256, 0, stream>>>(h_bf, aggrb, nullptr, nullptr, Wt_u1[l],
        nullptr, nullptr, u1b, st2, NATOMS, 512, 256, 0);
    bnap_k<0><<<2048, 256, 0, stream>>>(u1b, nullptr, u1b, st2,
        upd_g1 + l * EMB, upd_be1 + l * EMB, (i64)NATOMS * EMB, 1.f / NATOMS);
    // u2
    mgemm_k<0, bf16><<<gN, 256, 0, stream>>>(u1b, nullptr, nullptr, nullptr, Wt_u2[l],
        nullptr, nullptr, u2b, st3, NATOMS, 256, 256, 0);
    // h = h + relu(bn(u2))
    bnap_k<1><<<2048, 256, 0, stream>>>(u2b, h_bf, h_bf, st3,
        upd_g2 + l * EMB, upd_be2 + l * EMB, (i64)NATOMS * EMB, 1.f / NATOMS);
  }

  // pool
  pool_seg_k<<<NB, 256, 0, stream>>>(h_bf, batch, g0b);

  // graph MLP + fp branch
  mgemm_k<0, bf16><<<dim3(8, 8), 256, 0, stream>>>(g0b, nullptr, nullptr, nullptr, Wt_gl1,
      gl_b1, nullptr, gh1b, nullptr, NB, 256, 1024, 1);
  mgemm_k<0, bf16><<<dim3(8, 8), 256, 0, stream>>>(gh1b, nullptr, nullptr, nullptr, Wt_gl2,
      gl_b2, nullptr, gh2b, nullptr, NB, 1024, 1024, 1);
  mgemm_k<0, float><<<dim3(4, 8), 256, 0, stream>>>(gh2b, nullptr, nullptr, nullptr, Wt_gl3,
      gl_b3, nullptr, g3, nullptr, NB, 1024, 512, 0);
  cvt_k<<<512, 256, 0, stream>>>(g3, g3b, (i64)NB * HIDF);
  cvt_k<<<512, 256, 0, stream>>>(fp, fpb, (i64)NB * 2048);
  mgemm_k<0, bf16><<<dim3(4, 8), 256, 0, stream>>>(fpb, nullptr, nullptr, nullptr, Wt_fp,
      fp_b, nullptr, fpfb, nullptr, NB, 2048, 512, 1);

  // attention 0: Q from fpf, K/V from g3; residual g3
  mgemm_k<0, float><<<dim3(4, 8), 256, 0, stream>>>(fpfb, nullptr, nullptr, nullptr, Wt_att[0],
      att_b + 0 * HIDF, nullptr, Qb, nullptr, NB, 512, 512, 0);
  mgemm_k<0, float><<<dim3(4, 8), 256, 0, stream>>>(g3b, nullptr, nullptr, nullptr, Wt_att[1],
      att_b + 1 * HIDF, nullptr, Kb, nullptr, NB, 512, 512, 0);
  mgemm_k<0, float><<<dim3(4, 8), 256, 0, stream>>>(g3b, nullptr, nullptr, nullptr, Wt_att[2],
      att_b + 2 * HIDF, nullptr, Vb, nullptr, NB, 512, 512, 0);
  attn_k<<<NB * NH, 64, 0, stream>>>(Qb, Kb, Vb, Obb);
  mgemm_k<0, float><<<dim3(4, 8), 256, 0, stream>>>(Obb, nullptr, nullptr, nullptr, Wt_att[3],
      att_b + 3 * HIDF, g3, gc1, nullptr, NB, 512, 512, 0);
  cvt_k<<<512, 256, 0, stream>>>(gc1, gc1b, (i64)NB * HIDF);

  // attention 1: self
  mgemm_k<0, float><<<dim3(4, 8), 256, 0, stream>>>(gc1b, nullptr, nullptr, nullptr, Wt_att[4],
      att_b + 4 * HIDF, nullptr, Qb, nullptr, NB, 512, 512, 0);
  mgemm_k<0, float><<<dim3(4, 8), 256, 0, stream>>>(gc1b, nullptr, nullptr, nullptr, Wt_att[5],
      att_b + 5 * HIDF, nullptr, Kb, nullptr, NB, 512, 512, 0);
  mgemm_k<0, float><<<dim3(4, 8), 256, 0, stream>>>(gc1b, nullptr, nullptr, nullptr, Wt_att[6],
      att_b + 6 * HIDF, nullptr, Vb, nullptr, NB, 512, 512, 0);
  attn_k<<<NB * NH, 64, 0, stream>>>(Qb, Kb, Vb, Obb);
  mgemm_k<0, float><<<dim3(4, 8), 256, 0, stream>>>(Obb, nullptr, nullptr, nullptr, Wt_att[7],
      att_b + 7 * HIDF, nullptr, gc2, nullptr, NB, 512, 512, 0);

  bind_loss_k<<<32, 256, 0, stream>>>(gc2, bind_w, bind_b, target, (float*)d_out);
}